// Round 7
// baseline (1517.611 us; speedup 1.0000x reference)
//
#include <hip/hip_runtime.h>

#define NN 100000
#define NE 3200000
#define HID 64
#define NPB 256                         // nodes per bucket (dl = dst & 255)
#define NB  ((NN + NPB - 1) / NPB)      // 391 buckets
#define CAP 9216                        // bucket capacity: mean 8192, +11 sigma
#define MNP 128                         // nodes per window
#define NMW (2 * NB)                    // 782 windows
#define CHUNK 4096                      // edges per scatter workgroup (proven R5 config)
#define NCH ((NE + CHUNK - 1) / CHUNK)  // 782 chunks
#define APF 68                          // f32 agg row pitch (272 B; bank advance 4 -> 2-way)
#define BPITCH 136                      // f16 Bt row pitch in halfs (272 B)
#define SRCM 0x1FFFF                    // src mask (17 bits; NN < 2^17)

typedef _Float16 half8 __attribute__((ext_vector_type(8)));
typedef float f32x4 __attribute__((ext_vector_type(4)));

// -------- init: sx = (0, x) so split-s1 merges via atomics; bucket cursors --------
__global__ __launch_bounds__(512) void k_init(const float* __restrict__ x,
                                              float2* __restrict__ sx,
                                              int* __restrict__ gcur) {
    const int i = blockIdx.x * 512 + threadIdx.x;
    if (i < NN) sx[i] = make_float2(0.f, x[i]);
    if (blockIdx.x == 0 && threadIdx.x < NB) gcur[threadIdx.x] = threadIdx.x * CAP;
}

// -------- scatter: in-LDS counting sort -> bucket-grouped coalesced emission ----
// CHUNK 4096 (R5-proven; 2048 raised write amplification 45->59 MB). No dlb.
__global__ __launch_bounds__(256) void k_scatter(const int* __restrict__ src,
                                                 const int* __restrict__ dst,
                                                 const float* __restrict__ ew,
                                                 int* __restrict__ gcur,
                                                 int2* __restrict__ rec) {
    __shared__ int2 lrec[CHUNK];              // 32 KB
    __shared__ unsigned short lb[CHUNK];      // 8 KB  (bucket id per record)
    __shared__ unsigned short sidx[CHUNK];    // 8 KB  (sorted-order -> record idx)
    __shared__ int cnt[NB];                   // counts, then cursor (=excl)
    __shared__ int bme[NB];                   // base - excl
    __shared__ int wt8[8];                    // wave scan partials
    const int tid = threadIdx.x;
    const int lane = tid & 63, wvx = tid >> 6;   // 4 waves
    for (int j = tid; j < NB; j += 256) cnt[j] = 0;
    __syncthreads();
    const long long b0 = (long long)blockIdx.x * CHUNK;
    const int valid = (int)min((long long)CHUNK, (long long)NE - b0);
    #pragma unroll
    for (int k = 0; k < CHUNK / 256; ++k) {
        int idx = k * 256 + tid;
        if (idx < valid) {
            long long e = b0 + idx;
            int d = dst[e];
            int b = d >> 8;
            lrec[idx] = make_int2(src[e] | ((d & 255) << 17), __float_as_int(ew[e]));
            lb[idx] = (unsigned short)b;
            atomicAdd(&cnt[b], 1);
        }
    }
    __syncthreads();
    // exclusive scan of 512 slots (NB=391 live) via per-wave shfl scans
    int v0 = (tid < NB) ? cnt[tid] : 0;
    int v1 = (tid + 256 < NB) ? cnt[tid + 256] : 0;
    int i0 = v0, i1 = v1;
    #pragma unroll
    for (int off = 1; off < 64; off <<= 1) {
        int t0 = __shfl_up(i0, off, 64);
        int t1 = __shfl_up(i1, off, 64);
        if (lane >= off) { i0 += t0; i1 += t1; }
    }
    if (lane == 63) { wt8[wvx] = i0; wt8[4 + wvx] = i1; }
    __syncthreads();
    int off0 = 0, off1 = 0;
    #pragma unroll
    for (int j = 0; j < 8; ++j) {
        int wt = wt8[j];
        if (j < wvx) off0 += wt;
        if (j < 4 + wvx) off1 += wt;
    }
    const int excl0 = off0 + i0 - v0;
    const int excl1 = off1 + i1 - v1;
    if (tid < NB) {
        int bb = v0 ? atomicAdd(&gcur[tid], v0) : 0;
        bme[tid] = bb - excl0;
        cnt[tid] = excl0;
    }
    if (tid + 256 < NB) {
        int bb = v1 ? atomicAdd(&gcur[tid + 256], v1) : 0;
        bme[tid + 256] = bb - excl1;
        cnt[tid + 256] = excl1;
    }
    __syncthreads();
    // placement: sorted position per record
    #pragma unroll
    for (int k = 0; k < CHUNK / 256; ++k) {
        int idx = k * 256 + tid;
        if (idx < valid) {
            int sp = atomicAdd(&cnt[lb[idx]], 1);
            sidx[sp] = (unsigned short)idx;
        }
    }
    __syncthreads();
    // emission in bucket order: consecutive lanes -> consecutive addresses per run
    #pragma unroll
    for (int k = 0; k < CHUNK / 256; ++k) {
        int sp = k * 256 + tid;
        if (sp < valid) {
            int idx = sidx[sp];
            int b = lb[idx];
            rec[bme[b] + sp] = lrec[idx];
        }
    }
}

// -------- split s1: 2 blocks/bucket, LDS partials -> clustered global atomics ----
__global__ __launch_bounds__(512) void k_s1(const int* __restrict__ gcur,
                                            const int2* __restrict__ rec,
                                            const float* __restrict__ x,
                                            float* __restrict__ sxf) {
    __shared__ float loc[NPB];
    if (threadIdx.x < NPB) loc[threadIdx.x] = 0.f;
    __syncthreads();
    const int wid = blockIdx.x;
    const int b = wid >> 1, j = wid & 1;
    const int beg = b * CAP, cnt = gcur[b] - beg;
    const int half = (cnt + 1) >> 1;
    const int s0 = beg + j * half;
    const int s1e = beg + min(cnt, j * half + half);
    for (int t = s0 + threadIdx.x; t < s1e; t += 512) {
        int2 rc = rec[t];
        atomicAdd(&loc[rc.x >> 17], __int_as_float(rc.y) * x[rc.x & SRCM]);
    }
    __syncthreads();
    const int i = b * NPB + threadIdx.x;
    if (threadIdx.x < NPB && i < NN) {
        float v = loc[threadIdx.x];
        if (v != 0.f) atomicAdd(&sxf[2 * i], v);
    }
}

// -------- agg: wave-per-edge, feature-per-lane, f32 LDS ds_add + MFMA epilogue ----
// One block per 128-node window. Replaces pack+mega: no dl-sort, no rec2 round trip.
// agg2[dl][f] += w * relu(s1[src]*W1r[f] + x[src]*W1t[f] + b1[f])   (w >= 0)
__global__ __launch_bounds__(512) void k_agg(
        const int* __restrict__ gcur,
        const int2* __restrict__ rec,
        const float2* __restrict__ sx,
        const float* __restrict__ W1_rel, const float* __restrict__ W1_root,
        const float* __restrict__ b1,
        const float* __restrict__ W2_rel, const float* __restrict__ b2,
        const float* __restrict__ W2_root,
        const float* __restrict__ W3_rel, const float* __restrict__ W3_root,
        const float* __restrict__ b3,
        float* __restrict__ p, float* __restrict__ out) {
    __shared__ float aggf[MNP * APF];         // 34816 B
    __shared__ _Float16 Bt[HID * BPITCH];     // 17408 B
    __shared__ float2 sxl[MNP];               // 1024 B -> 53.2 KB, 3 blocks/CU
    const int tid = threadIdx.x;
    const int f = tid & 63;
    const int wv = tid >> 6;                  // 0..7
    const int wid = blockIdx.x;
    const int b = wid >> 1;
    const unsigned h = (unsigned)(wid & 1);
    const int gi0 = wid * MNP;

    for (int j = tid; j < MNP * APF; j += 512) aggf[j] = 0.f;
    for (int idx = tid; idx < HID * HID; idx += 512) {
        int k = idx >> 6, n = idx & 63;
        Bt[n * BPITCH + k]       = (_Float16)W2_rel[idx];
        Bt[n * BPITCH + HID + k] = (_Float16)W2_root[idx];
    }
    if (tid < MNP) {
        int gi = gi0 + tid;
        sxl[tid] = (gi < NN) ? sx[gi] : make_float2(0.f, 0.f);
    }
    const float w1rf = W1_rel[f], w1tf = W1_root[f], b1ff = b1[f];
    const float b3v = b3[0];
    __syncthreads();

    // -------- edge stream: 8 waves split the bucket; wave handles 1 edge/iter --------
    {
        const int beg = b * CAP;
        const int cnt = __builtin_amdgcn_readfirstlane(gcur[b]) - beg;
        const int span = ((cnt + 15) >> 4) << 1;          // even, 8*span >= cnt
        int lo = min(cnt, wv * span);
        int hi = min(cnt, lo + span);
        lo = __builtin_amdgcn_readfirstlane(lo);
        hi = __builtin_amdgcn_readfirstlane(hi);
        const int4* rp = (const int4*)(rec + beg);        // beg even -> 16B aligned

// decode record + issue sx gather (wave-uniform) for slot n
#define ISSUE(n, RX, RY)                                                  \
        const bool m##n = ((((unsigned)(RX)) >> 24) & 1u) == h;           \
        const int row##n = ((RX) >> 17) & 127;                            \
        const float w##n = __int_as_float(RY);                            \
        float2 s##n;                                                      \
        if (m##n) s##n = sx[(RX) & SRCM];
// compute + LDS f32 atomic for slot n
#define COMP(n)                                                           \
        if (m##n) {                                                       \
            const float t_ = fmaf(s##n.x, w1rf, fmaf(s##n.y, w1tf, b1ff));\
            atomicAdd(&aggf[row##n * APF + f], w##n * fmaxf(t_, 0.f));    \
        }

        int i = lo;
        int4 qa, qb, qc, qd;
        bool have = (i + 8 <= hi);
        if (have) {
            const int4* r0 = rp + (i >> 1);
            qa = r0[0]; qb = r0[1]; qc = r0[2]; qd = r0[3];
        }
        while (have) {
            int4 na, nb, nc, nd;
            const bool nxt = (i + 16 <= hi);
            if (nxt) {
                const int4* r1 = rp + ((i + 8) >> 1);
                na = r1[0]; nb = r1[1]; nc = r1[2]; nd = r1[3];
            }
            // issue all 8 sx gathers up front, then compute (ILP batch of 8)
            ISSUE(0, qa.x, qa.y) ISSUE(1, qa.z, qa.w)
            ISSUE(2, qb.x, qb.y) ISSUE(3, qb.z, qb.w)
            ISSUE(4, qc.x, qc.y) ISSUE(5, qc.z, qc.w)
            ISSUE(6, qd.x, qd.y) ISSUE(7, qd.z, qd.w)
            COMP(0) COMP(1) COMP(2) COMP(3)
            COMP(4) COMP(5) COMP(6) COMP(7)
            i += 8;
            have = nxt;
            if (nxt) { qa = na; qb = nb; qc = nc; qd = nd; }
        }
        for (; i < hi; ++i) {
            int2 rc = rec[beg + i];
            ISSUE(9, rc.x, rc.y)
            COMP(9)
        }
#undef ISSUE
#undef COMP
    }
    __syncthreads();

    // -------- MFMA layer-2 + fused layer-3 epilogue (A from f32 agg tile) --------
    const int m16 = tid & 15;
    const int quad = (tid & 63) >> 4;
    f32x4 acc[4];
    #pragma unroll
    for (int c_ = 0; c_ < 4; ++c_) acc[c_] = (f32x4){0.f, 0.f, 0.f, 0.f};

    const float2 sm = sxl[wv * 16 + m16];

    #pragma unroll
    for (int kt = 0; kt < 4; ++kt) {
        const int kk = kt * 32;
        half8 af;
        if (kt < 2) {
            const float* ar = &aggf[(wv * 16 + m16) * APF + kk + quad * 8];
            const f32x4 u0 = *(const f32x4*)ar;
            const f32x4 u1 = *(const f32x4*)(ar + 4);
            #pragma unroll
            for (int j = 0; j < 4; ++j) {
                af[j]     = (_Float16)u0[j];
                af[4 + j] = (_Float16)u1[j];
            }
        } else {
            const int fk0 = (kt - 2) * 32 + quad * 8;
            #pragma unroll
            for (int j = 0; j < 8; ++j) {
                const float wr = W1_rel[fk0 + j], wt = W1_root[fk0 + j], bb = b1[fk0 + j];
                af[j] = (_Float16)fmaxf(0.f, fmaf(sm.x, wr, fmaf(sm.y, wt, bb)));
            }
        }
        #pragma unroll
        for (int ct = 0; ct < 4; ++ct) {
            const half8 bfrag = *(const half8*)&Bt[(ct * 16 + m16) * BPITCH + kk + quad * 8];
            acc[ct] = __builtin_amdgcn_mfma_f32_16x16x32_f16(af, bfrag, acc[ct], 0, 0, 0);
        }
    }

    float b2c[4], w3rc[4], w3tc[4];
    #pragma unroll
    for (int ct = 0; ct < 4; ++ct) {
        const int col = ct * 16 + m16;
        b2c[ct] = b2[col]; w3rc[ct] = W3_rel[col]; w3tc[ct] = W3_root[col];
    }
    float pv[4] = {0.f, 0.f, 0.f, 0.f}, rv[4] = {0.f, 0.f, 0.f, 0.f};
    #pragma unroll
    for (int ct = 0; ct < 4; ++ct) {
        #pragma unroll
        for (int reg = 0; reg < 4; ++reg) {
            const float h2_ = fmaxf(0.f, acc[ct][reg] + b2c[ct]);
            pv[reg] = fmaf(h2_, w3rc[ct], pv[reg]);
            rv[reg] = fmaf(h2_, w3tc[ct], rv[reg]);
        }
    }
    #pragma unroll
    for (int reg = 0; reg < 4; ++reg) {
        #pragma unroll
        for (int msk = 1; msk < 16; msk <<= 1) {
            pv[reg] += __shfl_xor(pv[reg], msk, 64);
            rv[reg] += __shfl_xor(rv[reg], msk, 64);
        }
    }
    if (m16 == 0) {
        #pragma unroll
        for (int reg = 0; reg < 4; ++reg) {
            const int gi = gi0 + wv * 16 + quad * 4 + reg;
            if (gi < NN) { p[gi] = pv[reg]; out[gi] = rv[reg] + b3v; }
        }
    }
}

// -------- split out: 2 blocks/bucket; out += seg_sum(w * p[src]) via atomics ----
__global__ __launch_bounds__(512) void k_out(const int* __restrict__ gcur,
                                             const int2* __restrict__ rec,
                                             const float* __restrict__ pp,
                                             float* __restrict__ out) {
    __shared__ float loc[NPB];
    if (threadIdx.x < NPB) loc[threadIdx.x] = 0.f;
    __syncthreads();
    const int wid = blockIdx.x;
    const int b = wid >> 1, j = wid & 1;
    const int beg = b * CAP, cnt = gcur[b] - beg;
    const int half = (cnt + 1) >> 1;
    const int s0 = beg + j * half;
    const int s1e = beg + min(cnt, j * half + half);
    for (int t = s0 + threadIdx.x; t < s1e; t += 512) {
        int2 rc = rec[t];
        atomicAdd(&loc[rc.x >> 17], __int_as_float(rc.y) * pp[rc.x & SRCM]);
    }
    __syncthreads();
    const int i = b * NPB + threadIdx.x;
    if (threadIdx.x < NPB && i < NN) {
        float v = loc[threadIdx.x];
        if (v != 0.f) atomicAdd(&out[i], v);
    }
}

extern "C" void kernel_launch(void* const* d_in, const int* in_sizes, int n_in,
                              void* d_out, int out_size, void* d_ws, size_t ws_size,
                              hipStream_t stream) {
    const float* x       = (const float*)d_in[0];
    const int*   ei      = (const int*)  d_in[1];
    const float* ew      = (const float*)d_in[2];
    const float* W1_rel  = (const float*)d_in[3];
    const float* b1      = (const float*)d_in[4];
    const float* W1_root = (const float*)d_in[5];
    const float* W2_rel  = (const float*)d_in[6];
    const float* b2      = (const float*)d_in[7];
    const float* W2_root = (const float*)d_in[8];
    const float* W3_rel  = (const float*)d_in[9];
    const float* b3      = (const float*)d_in[10];
    const float* W3_root = (const float*)d_in[11];

    const int* src = ei;
    const int* dst = ei + NE;

    // workspace layout (~31 MB of the ~268 MB workspace)
    const size_t REC_SLOTS = (size_t)NB * CAP;            // 3.60M slots, 28.8 MB
    int2*   rec  = (int2*)d_ws;
    float2* sx   = (float2*)(rec + REC_SLOTS);            // 800 KB
    float*  p    = (float*)(sx + NN);                     // 400 KB
    int*    gcur = (int*)(p + NN);                        // NB*4

    k_init<<<(NN + 511) / 512, 512, 0, stream>>>(x, sx, gcur);
    k_scatter<<<NCH, 256, 0, stream>>>(src, dst, ew, gcur, rec);
    k_s1<<<2 * NB, 512, 0, stream>>>(gcur, rec, x, (float*)sx);
    k_agg<<<NMW, 512, 0, stream>>>(gcur, rec, sx,
                                   W1_rel, W1_root, b1,
                                   W2_rel, b2, W2_root,
                                   W3_rel, W3_root, b3, p, (float*)d_out);
    k_out<<<2 * NB, 512, 0, stream>>>(gcur, rec, p, (float*)d_out);
}

// Round 8
// 252.637 us; speedup vs baseline: 6.0071x; 6.0071x over previous
//
#include <hip/hip_runtime.h>

#define NN 100000
#define NE 3200000
#define HID 64
#define NPB 256                         // nodes per bucket (dl = dst & 255)
#define NB  ((NN + NPB - 1) / NPB)      // 391 buckets
#define NNP (NB * NPB)                  // 100096 padded node slots
#define CAP 9216                        // bucket capacity: mean 8192, +11 sigma
#define MNP 128                         // nodes per window
#define NMW (2 * NB)                    // 782 windows
#define CAPW 5120                       // padded slots per window: mean ~4544, +8.7 sigma
#define CHUNK 4096                      // edges per scatter workgroup (R5-proven)
#define NCH ((NE + CHUNK - 1) / CHUNK)  // 782 chunks
#define AP 72                           // f16 agg row pitch in halfs (144 B)
#define BPITCH 136                      // f16 Bt row pitch in halfs (272 B)
#define SRCM 0x1FFFF                    // src mask (17 bits; NN < 2^17)

typedef _Float16 half8 __attribute__((ext_vector_type(8)));
typedef _Float16 h2v   __attribute__((ext_vector_type(2)));
typedef float f32x4 __attribute__((ext_vector_type(4)));

__device__ __forceinline__ unsigned short f2hb(float v) {
    _Float16 h = (_Float16)v;
    unsigned short s;
    __builtin_memcpy(&s, &h, 2);
    return s;
}
__device__ __forceinline__ h2v ash2(unsigned int u) {
    h2v r;
    __builtin_memcpy(&r, &u, 4);
    return r;
}

// -------- init: sx = (0, x) so split-s1 merges via atomics; bucket cursors --------
__global__ __launch_bounds__(512) void k_init(const float* __restrict__ x,
                                              float2* __restrict__ sx,
                                              int* __restrict__ gcur) {
    const int i = blockIdx.x * 512 + threadIdx.x;
    if (i < NN) sx[i] = make_float2(0.f, x[i]);
    if (blockIdx.x == 0 && threadIdx.x < NB) gcur[threadIdx.x] = threadIdx.x * CAP;
}

// -------- scatter: in-LDS counting sort -> bucket-grouped coalesced emission ----
__global__ __launch_bounds__(256) void k_scatter(const int* __restrict__ src,
                                                 const int* __restrict__ dst,
                                                 const float* __restrict__ ew,
                                                 int* __restrict__ gcur,
                                                 int2* __restrict__ rec,
                                                 unsigned char* __restrict__ dlb) {
    __shared__ int2 lrec[CHUNK];              // 32 KB
    __shared__ unsigned short lb[CHUNK];      // 8 KB  (bucket id per record)
    __shared__ unsigned short sidx[CHUNK];    // 8 KB  (sorted-order -> record idx)
    __shared__ int cnt[NB];                   // counts, then cursor (=excl)
    __shared__ int bme[NB];                   // base - excl
    __shared__ int wt8[8];                    // wave scan partials
    const int tid = threadIdx.x;
    const int lane = tid & 63, wvx = tid >> 6;   // 4 waves
    for (int j = tid; j < NB; j += 256) cnt[j] = 0;
    __syncthreads();
    const long long b0 = (long long)blockIdx.x * CHUNK;
    const int valid = (int)min((long long)CHUNK, (long long)NE - b0);
    #pragma unroll
    for (int k = 0; k < CHUNK / 256; ++k) {
        int idx = k * 256 + tid;
        if (idx < valid) {
            long long e = b0 + idx;
            int d = dst[e];
            int b = d >> 8;
            lrec[idx] = make_int2(src[e] | ((d & 255) << 17), __float_as_int(ew[e]));
            lb[idx] = (unsigned short)b;
            atomicAdd(&cnt[b], 1);
        }
    }
    __syncthreads();
    // exclusive scan of 512 slots (NB=391 live) via per-wave shfl scans
    int v0 = (tid < NB) ? cnt[tid] : 0;
    int v1 = (tid + 256 < NB) ? cnt[tid + 256] : 0;
    int i0 = v0, i1 = v1;
    #pragma unroll
    for (int off = 1; off < 64; off <<= 1) {
        int t0 = __shfl_up(i0, off, 64);
        int t1 = __shfl_up(i1, off, 64);
        if (lane >= off) { i0 += t0; i1 += t1; }
    }
    if (lane == 63) { wt8[wvx] = i0; wt8[4 + wvx] = i1; }
    __syncthreads();
    int off0 = 0, off1 = 0;
    #pragma unroll
    for (int j = 0; j < 8; ++j) {
        int wt = wt8[j];
        if (j < wvx) off0 += wt;
        if (j < 4 + wvx) off1 += wt;
    }
    const int excl0 = off0 + i0 - v0;
    const int excl1 = off1 + i1 - v1;
    if (tid < NB) {
        int bb = v0 ? atomicAdd(&gcur[tid], v0) : 0;
        bme[tid] = bb - excl0;
        cnt[tid] = excl0;
    }
    if (tid + 256 < NB) {
        int bb = v1 ? atomicAdd(&gcur[tid + 256], v1) : 0;
        bme[tid + 256] = bb - excl1;
        cnt[tid + 256] = excl1;
    }
    __syncthreads();
    // placement: sorted position per record
    #pragma unroll
    for (int k = 0; k < CHUNK / 256; ++k) {
        int idx = k * 256 + tid;
        if (idx < valid) {
            int sp = atomicAdd(&cnt[lb[idx]], 1);
            sidx[sp] = (unsigned short)idx;
        }
    }
    __syncthreads();
    // emission in bucket order: consecutive lanes -> consecutive addresses per run
    #pragma unroll
    for (int k = 0; k < CHUNK / 256; ++k) {
        int sp = k * 256 + tid;
        if (sp < valid) {
            int idx = sidx[sp];
            int b = lb[idx];
            int2 rc = lrec[idx];
            int go = bme[b] + sp;
            rec[go] = rc;
            dlb[go] = (unsigned char)((rc.x >> 17) & 255);
        }
    }
}

// -------- split s1: 2 blocks/bucket, LDS partials -> clustered global atomics ----
__global__ __launch_bounds__(512) void k_s1(const int* __restrict__ gcur,
                                            const int2* __restrict__ rec,
                                            const float* __restrict__ x,
                                            float* __restrict__ sxf) {
    __shared__ float loc[NPB];
    if (threadIdx.x < NPB) loc[threadIdx.x] = 0.f;
    __syncthreads();
    const int wid = blockIdx.x;
    const int b = wid >> 1, j = wid & 1;
    const int beg = b * CAP, cnt = gcur[b] - beg;
    const int half = (cnt + 1) >> 1;
    const int s0 = beg + j * half;
    const int s1e = beg + min(cnt, j * half + half);
    for (int t = s0 + threadIdx.x; t < s1e; t += 512) {
        int2 rc = rec[t];
        atomicAdd(&loc[rc.x >> 17], __int_as_float(rc.y) * x[rc.x & SRCM]);
    }
    __syncthreads();
    const int i = b * NPB + threadIdx.x;
    if (threadIdx.x < NPB && i < NN) {
        float v = loc[threadIdx.x];
        if (v != 0.f) atomicAdd(&sxf[2 * i], v);
    }
}

// -------- pack: per-window LDS rec2 image (scattered u16 -> LDS), coalesced dump ----
__global__ __launch_bounds__(512) void k_pack(const int* __restrict__ gcur,
                                              const int2* __restrict__ rec,
                                              const unsigned char* __restrict__ dlb,
                                              const float2* __restrict__ sx,
                                              int4* __restrict__ rec2q,
                                              int* __restrict__ noff,
                                              unsigned char* __restrict__ ngrp) {
    __shared__ int4 img4[CAPW / 2];           // 40960 B
    __shared__ int hist[128];
    __shared__ int exclp[128];
    __shared__ int cur[128];
    __shared__ int wt2[2];
    unsigned short* imgh = (unsigned short*)img4;
    const int tid = threadIdx.x;
    const int lane = tid & 63, wv = tid >> 6;
    const int wid = blockIdx.x;
    const int b = wid >> 1, h = wid & 1;
    for (int j = tid; j < CAPW / 2; j += 512) img4[j] = (int4){0, 0, 0, 0};
    if (tid < 128) hist[tid] = 0;
    __syncthreads();
    const int beg = b * CAP;
    const int cnt = gcur[b] - beg;
    // histogram of our half from compact dlb stream (uchar4 loads)
    {
        const uchar4* d4 = (const uchar4*)(dlb + beg);
        const int n4 = cnt >> 2;
        for (int t = tid; t < n4; t += 512) {
            uchar4 q = d4[t];
            if ((q.x >> 7) == h) atomicAdd(&hist[q.x & 127], 1);
            if ((q.y >> 7) == h) atomicAdd(&hist[q.y & 127], 1);
            if ((q.z >> 7) == h) atomicAdd(&hist[q.z & 127], 1);
            if ((q.w >> 7) == h) atomicAdd(&hist[q.w & 127], 1);
        }
        for (int t = (n4 << 2) + tid; t < cnt; t += 512) {
            int dl = dlb[beg + t];
            if ((dl >> 7) == h) atomicAdd(&hist[dl & 127], 1);
        }
    }
    __syncthreads();
    // padded exclusive scan over 128 bins (waves 0-1 live)
    int pc = 0, incl = 0;
    if (tid < 128) { pc = (hist[tid] + 7) & ~7; incl = pc; }
    #pragma unroll
    for (int off = 1; off < 64; off <<= 1) {
        int tt = __shfl_up(incl, off, 64);
        if (lane >= off) incl += tt;
    }
    if (tid < 128 && lane == 63) wt2[wv] = incl;
    __syncthreads();
    if (tid < 128) {
        int e0 = ((tid >= 64) ? wt2[0] : 0) + incl - pc;
        exclp[tid] = e0;
        cur[tid] = e0;
        const int node = wid * MNP + tid;
        noff[node] = wid * CAPW + e0;         // absolute slot offset (mult of 8)
        ngrp[node] = (unsigned char)(pc >> 3);
    }
    __syncthreads();
    // pass2: stream rec (int4 = 2 records), gather sx, scatter into LDS image
#define PREC(RX, RY) {                                                  \
        const int dl_ = ((RX) >> 17) & 255;                             \
        if ((dl_ >> 7) == h) {                                          \
            const float w_ = __int_as_float(RY);                        \
            const float2 v_ = sx[(RX) & SRCM];                          \
            int gs_ = atomicAdd(&cur[dl_ & 127], 1);                    \
            int hb_ = (gs_ >> 1) * 8 + (gs_ & 1);                       \
            imgh[hb_]     = f2hb(w_ * v_.x);                            \
            imgh[hb_ + 2] = f2hb(w_ * v_.y);                            \
            imgh[hb_ + 4] = f2hb(w_);                                   \
        } }
    {
        const int4* r4 = (const int4*)(rec + beg);
        const int n2 = cnt >> 1;
        for (int t = tid; t < n2; t += 512) {
            int4 q = r4[t];
            PREC(q.x, q.y)
            PREC(q.z, q.w)
        }
        for (int t = (n2 << 1) + tid; t < cnt; t += 512) {
            int2 rc = rec[beg + t];
            PREC(rc.x, rc.y)
        }
    }
#undef PREC
    __syncthreads();
    // coalesced dump: 40960 B per window
    int4* d4 = rec2q + (size_t)wid * (CAPW / 2);
    for (int j = tid; j < CAPW / 2; j += 512) d4[j] = img4[j];
}

// -------- mega: branchless pair stream (4-deep prefetch) + MFMA --------
// Writes p and out = rv + b3 (k_out atomically adds the aggregation term).
__global__ __launch_bounds__(512) void k_mega(
        const int* __restrict__ noff, const unsigned char* __restrict__ ngrp,
        const char* __restrict__ rec2b, const float2* __restrict__ sx,
        const float* __restrict__ W1_rel, const float* __restrict__ W1_root,
        const float* __restrict__ b1,
        const float* __restrict__ W2_rel, const float* __restrict__ b2,
        const float* __restrict__ W2_root,
        const float* __restrict__ W3_rel, const float* __restrict__ W3_root,
        const float* __restrict__ b3,
        float* __restrict__ p, float* __restrict__ out) {
    __shared__ _Float16 aggh[MNP * AP];       // 18432 B
    __shared__ _Float16 Bt[HID * BPITCH];     // 17408 B
    __shared__ float2 sxl[MNP];               // 1024 B -> 36.9 KB
    const int tid = threadIdx.x;
    const int f = tid & 63;
    const int wv = tid >> 6;                  // 0..7
    const int gi0 = blockIdx.x * MNP;

    for (int j = tid; j < MNP * AP / 2; j += 512) ((int*)aggh)[j] = 0;
    for (int idx = tid; idx < HID * HID; idx += 512) {
        int k = idx >> 6, n = idx & 63;
        Bt[n * BPITCH + k]       = (_Float16)W2_rel[idx];
        Bt[n * BPITCH + HID + k] = (_Float16)W2_root[idx];
    }
    if (tid < MNP) {
        int gi = gi0 + tid;
        sxl[tid] = (gi < NN) ? sx[gi] : make_float2(0.f, 0.f);
    }
    const float w1rf = W1_rel[f], w1tf = W1_root[f], b1ff = b1[f];
    const float b3v = b3[0];
    __syncthreads();

    {
        const int first = gi0 + wv * 16;
        int soff = __builtin_amdgcn_readfirstlane(noff[first]);
        const int4 gvv = *(const int4*)(ngrp + first);
        unsigned ua = __builtin_amdgcn_readfirstlane((unsigned)gvv.x);
        unsigned ub = __builtin_amdgcn_readfirstlane((unsigned)gvv.y);
        unsigned uc = __builtin_amdgcn_readfirstlane((unsigned)gvv.z);
        unsigned ud = __builtin_amdgcn_readfirstlane((unsigned)gvv.w);
        unsigned long long clo = (unsigned long long)ua | ((unsigned long long)ub << 32);
        unsigned long long chi = (unsigned long long)uc | ((unsigned long long)ud << 32);
        #define BSUM(u) (((u) & 255u) + (((u) >> 8) & 255u) + (((u) >> 16) & 255u) + ((u) >> 24))
        const int tg = (int)(BSUM(ua) + BSUM(ub) + BSUM(uc) + BSUM(ud));
        #undef BSUM

        const h2v w1r2 = {(_Float16)w1rf, (_Float16)w1rf};
        const h2v w1t2 = {(_Float16)w1tf, (_Float16)w1tf};
        const h2v b1f2 = {(_Float16)b1ff, (_Float16)b1ff};
        const h2v one2 = {(_Float16)1.f, (_Float16)1.f};
        const h2v zero2 = {(_Float16)0.f, (_Float16)0.f};

        float a0 = 0.f, a1 = 0.f, a2 = 0.f, a3 = 0.f;
        int nrow = wv * 16;
        const int rowend = nrow + 16;
        int grem = (int)(clo & 255); clo = (clo >> 8) | (chi << 56); chi >>= 8;
        while (grem == 0 && nrow + 1 < rowend) {
            ++nrow; grem = (int)(clo & 255);
            clo = (clo >> 8) | (chi << 56); chi >>= 8;
        }

        const int4* rp = (const int4*)rec2b + (soff >> 1);
        int4 A0, A1, A2, A3, B0, B1, B2, B3, C0, C1, C2, C3, D0, D1, D2, D3;
        if (tg >= 1) { A0 = rp[0]; A1 = rp[1]; A2 = rp[2];  A3 = rp[3]; }
        if (tg >= 2) { B0 = rp[4]; B1 = rp[5]; B2 = rp[6];  B3 = rp[7]; }
        if (tg >= 3) { C0 = rp[8]; C1 = rp[9]; C2 = rp[10]; C3 = rp[11]; }
        rp += 12;

#define PP(Q, AA) {                                          \
        h2v z_ = ash2((unsigned)(Q).z) * b1f2;               \
        z_ = ash2((unsigned)(Q).y) * w1t2 + z_;              \
        z_ = ash2((unsigned)(Q).x) * w1r2 + z_;              \
        z_ = __builtin_elementwise_max(z_, zero2);           \
        AA = __builtin_amdgcn_fdot2(z_, one2, AA, false); }

#define BNDRY() {                                                        \
        if (--grem == 0) {                                               \
            aggh[nrow * AP + f] = (_Float16)((a0 + a1) + (a2 + a3));     \
            a0 = a1 = a2 = a3 = 0.f;                                     \
            ++nrow; grem = (int)(clo & 255);                             \
            clo = (clo >> 8) | (chi << 56); chi >>= 8;                   \
            while (grem == 0 && nrow + 1 < rowend) {                     \
                ++nrow; grem = (int)(clo & 255);                         \
                clo = (clo >> 8) | (chi << 56); chi >>= 8;               \
            }                                                            \
        } }

        int t = 0;
        // steady state: 4 groups in flight
        while (t + 4 <= tg) {
            D0 = rp[0]; D1 = rp[1]; D2 = rp[2]; D3 = rp[3];
            PP(A0, a0) PP(A1, a1) PP(A2, a2) PP(A3, a3) BNDRY(); ++t;
            A0 = rp[4]; A1 = rp[5]; A2 = rp[6]; A3 = rp[7];
            PP(B0, a0) PP(B1, a1) PP(B2, a2) PP(B3, a3) BNDRY(); ++t;
            B0 = rp[8]; B1 = rp[9]; B2 = rp[10]; B3 = rp[11];
            PP(C0, a0) PP(C1, a1) PP(C2, a2) PP(C3, a3) BNDRY(); ++t;
            C0 = rp[12]; C1 = rp[13]; C2 = rp[14]; C3 = rp[15];
            PP(D0, a0) PP(D1, a1) PP(D2, a2) PP(D3, a3) BNDRY(); ++t;
            rp += 16;
        }
        if (t < tg) {
            PP(A0, a0) PP(A1, a1) PP(A2, a2) PP(A3, a3) BNDRY(); ++t;
            if (t < tg) {
                PP(B0, a0) PP(B1, a1) PP(B2, a2) PP(B3, a3) BNDRY(); ++t;
                if (t < tg) {
                    PP(C0, a0) PP(C1, a1) PP(C2, a2) PP(C3, a3) BNDRY(); ++t;
                }
            }
        }
#undef PP
#undef BNDRY
    }
    __syncthreads();

    const int m16 = tid & 15;
    const int quad = (tid & 63) >> 4;
    f32x4 acc[4];
    #pragma unroll
    for (int c_ = 0; c_ < 4; ++c_) acc[c_] = (f32x4){0.f, 0.f, 0.f, 0.f};

    const float2 sm = sxl[wv * 16 + m16];

    #pragma unroll
    for (int kt = 0; kt < 4; ++kt) {
        const int kk = kt * 32;
        half8 af;
        if (kt < 2) {
            af = *(const half8*)&aggh[(wv * 16 + m16) * AP + kk + quad * 8];
        } else {
            const int fk0 = (kt - 2) * 32 + quad * 8;
            #pragma unroll
            for (int j = 0; j < 8; ++j) {
                const float wr = W1_rel[fk0 + j], wt = W1_root[fk0 + j], bb = b1[fk0 + j];
                af[j] = (_Float16)fmaxf(0.f, fmaf(sm.x, wr, fmaf(sm.y, wt, bb)));
            }
        }
        #pragma unroll
        for (int ct = 0; ct < 4; ++ct) {
            const half8 bfrag = *(const half8*)&Bt[(ct * 16 + m16) * BPITCH + kk + quad * 8];
            acc[ct] = __builtin_amdgcn_mfma_f32_16x16x32_f16(af, bfrag, acc[ct], 0, 0, 0);
        }
    }

    float b2c[4], w3rc[4], w3tc[4];
    #pragma unroll
    for (int ct = 0; ct < 4; ++ct) {
        const int col = ct * 16 + m16;
        b2c[ct] = b2[col]; w3rc[ct] = W3_rel[col]; w3tc[ct] = W3_root[col];
    }
    float pv[4] = {0.f, 0.f, 0.f, 0.f}, rv[4] = {0.f, 0.f, 0.f, 0.f};
    #pragma unroll
    for (int ct = 0; ct < 4; ++ct) {
        #pragma unroll
        for (int reg = 0; reg < 4; ++reg) {
            const float h2_ = fmaxf(0.f, acc[ct][reg] + b2c[ct]);
            pv[reg] = fmaf(h2_, w3rc[ct], pv[reg]);
            rv[reg] = fmaf(h2_, w3tc[ct], rv[reg]);
        }
    }
    #pragma unroll
    for (int reg = 0; reg < 4; ++reg) {
        #pragma unroll
        for (int msk = 1; msk < 16; msk <<= 1) {
            pv[reg] += __shfl_xor(pv[reg], msk, 64);
            rv[reg] += __shfl_xor(rv[reg], msk, 64);
        }
    }
    if (m16 == 0) {
        #pragma unroll
        for (int reg = 0; reg < 4; ++reg) {
            const int gi = gi0 + wv * 16 + quad * 4 + reg;
            if (gi < NN) { p[gi] = pv[reg]; out[gi] = rv[reg] + b3v; }
        }
    }
}

// -------- split out: 2 blocks/bucket; out += seg_sum(w * p[src]) via atomics ----
__global__ __launch_bounds__(512) void k_out(const int* __restrict__ gcur,
                                             const int2* __restrict__ rec,
                                             const float* __restrict__ pp,
                                             float* __restrict__ out) {
    __shared__ float loc[NPB];
    if (threadIdx.x < NPB) loc[threadIdx.x] = 0.f;
    __syncthreads();
    const int wid = blockIdx.x;
    const int b = wid >> 1, j = wid & 1;
    const int beg = b * CAP, cnt = gcur[b] - beg;
    const int half = (cnt + 1) >> 1;
    const int s0 = beg + j * half;
    const int s1e = beg + min(cnt, j * half + half);
    for (int t = s0 + threadIdx.x; t < s1e; t += 512) {
        int2 rc = rec[t];
        atomicAdd(&loc[rc.x >> 17], __int_as_float(rc.y) * pp[rc.x & SRCM]);
    }
    __syncthreads();
    const int i = b * NPB + threadIdx.x;
    if (threadIdx.x < NPB && i < NN) {
        float v = loc[threadIdx.x];
        if (v != 0.f) atomicAdd(&out[i], v);
    }
}

extern "C" void kernel_launch(void* const* d_in, const int* in_sizes, int n_in,
                              void* d_out, int out_size, void* d_ws, size_t ws_size,
                              hipStream_t stream) {
    const float* x       = (const float*)d_in[0];
    const int*   ei      = (const int*)  d_in[1];
    const float* ew      = (const float*)d_in[2];
    const float* W1_rel  = (const float*)d_in[3];
    const float* b1      = (const float*)d_in[4];
    const float* W1_root = (const float*)d_in[5];
    const float* W2_rel  = (const float*)d_in[6];
    const float* b2      = (const float*)d_in[7];
    const float* W2_root = (const float*)d_in[8];
    const float* W3_rel  = (const float*)d_in[9];
    const float* b3      = (const float*)d_in[10];
    const float* W3_root = (const float*)d_in[11];

    const int* src = ei;
    const int* dst = ei + NE;

    // workspace layout (~66 MB of the ~268 MB workspace)
    const size_t REC_SLOTS = (size_t)NB * CAP;            // 3.60M slots, 28.8 MB
    int2*          rec   = (int2*)d_ws;
    float2*        sx    = (float2*)(rec + REC_SLOTS);    // 800 KB
    float*         p     = (float*)(sx + NN);             // 400 KB
    int*           noff  = (int*)(p + NN);                // NNP*4
    unsigned char* ngrp  = (unsigned char*)(noff + NNP);  // NNP
    int*           gcur  = (int*)(ngrp + NNP);            // NB*4
    unsigned char* dlb   = (unsigned char*)(gcur + NB);   // NB*CAP = 3.6 MB
    char*          tail  = (char*)(dlb + REC_SLOTS);
    size_t         off   = ((size_t)(tail - (char*)d_ws) + 15) & ~(size_t)15;
    char*          rec2  = (char*)d_ws + off;             // NMW*CAPW*8 = 32.0 MB

    k_init<<<(NN + 511) / 512, 512, 0, stream>>>(x, sx, gcur);
    k_scatter<<<NCH, 256, 0, stream>>>(src, dst, ew, gcur, rec, dlb);
    k_s1<<<2 * NB, 512, 0, stream>>>(gcur, rec, x, (float*)sx);
    k_pack<<<NMW, 512, 0, stream>>>(gcur, rec, dlb, sx, (int4*)rec2, noff, ngrp);
    k_mega<<<NMW, 512, 0, stream>>>(noff, ngrp, rec2, sx,
                                    W1_rel, W1_root, b1,
                                    W2_rel, b2, W2_root,
                                    W3_rel, W3_root, b3, p, (float*)d_out);
    k_out<<<2 * NB, 512, 0, stream>>>(gcur, rec, p, (float*)d_out);
}

// Round 9
// 247.576 us; speedup vs baseline: 6.1299x; 1.0204x over previous
//
#include <hip/hip_runtime.h>

#define NN 100000
#define NE 3200000
#define HID 64
#define NPB 256                         // nodes per bucket (dl = dst & 255)
#define NB  ((NN + NPB - 1) / NPB)      // 391 buckets
#define NNP (NB * NPB)                  // 100096 padded node slots
#define CAP 9216                        // bucket capacity: mean 8192, +11 sigma
#define MNP 128                         // nodes per window
#define NMW (2 * NB)                    // 782 windows
#define CAPW 5120                       // padded slots per window: mean ~4544, +8.7 sigma
#define CHUNK 4096                      // edges per scatter workgroup (R5-proven)
#define NCH ((NE + CHUNK - 1) / CHUNK)  // 782 chunks
#define AP 72                           // f16 agg row pitch in halfs (144 B)
#define BPITCH 136                      // f16 Bt row pitch in halfs (272 B)
#define SRCM 0x1FFFF                    // src mask (17 bits; NN < 2^17)

typedef _Float16 half8 __attribute__((ext_vector_type(8)));
typedef _Float16 h2v   __attribute__((ext_vector_type(2)));
typedef float f32x4 __attribute__((ext_vector_type(4)));

__device__ __forceinline__ unsigned short f2hb(float v) {
    _Float16 h = (_Float16)v;
    unsigned short s;
    __builtin_memcpy(&s, &h, 2);
    return s;
}
__device__ __forceinline__ float h2f(unsigned int u) {
    unsigned short s = (unsigned short)u;
    _Float16 h;
    __builtin_memcpy(&h, &s, 2);
    return (float)h;
}
__device__ __forceinline__ h2v ash2(unsigned int u) {
    h2v r;
    __builtin_memcpy(&r, &u, 4);
    return r;
}

// -------- init: sx = (0, x) so split-s1 merges via atomics; bucket cursors --------
__global__ __launch_bounds__(512) void k_init(const float* __restrict__ x,
                                              float2* __restrict__ sx,
                                              int* __restrict__ gcur) {
    const int i = blockIdx.x * 512 + threadIdx.x;
    if (i < NN) sx[i] = make_float2(0.f, x[i]);
    if (blockIdx.x == 0 && threadIdx.x < NB) gcur[threadIdx.x] = threadIdx.x * CAP;
}

// -------- scatter: in-LDS counting sort -> bucket-grouped SoA emission ----
// rec_a = src | dl<<17 (4B), rec_w = f16 weight (2B). LDS 43.5 KB -> 3 blk/CU.
__global__ __launch_bounds__(256) void k_scatter(const int* __restrict__ src,
                                                 const int* __restrict__ dst,
                                                 const float* __restrict__ ew,
                                                 int* __restrict__ gcur,
                                                 int* __restrict__ rec_a,
                                                 unsigned short* __restrict__ rec_w) {
    __shared__ int la[CHUNK];                 // 16 KB
    __shared__ unsigned short lw[CHUNK];      // 8 KB
    __shared__ unsigned short lb[CHUNK];      // 8 KB  (bucket id per record)
    __shared__ unsigned short sidx[CHUNK];    // 8 KB  (sorted-order -> record idx)
    __shared__ int cnt[NB];                   // counts, then cursor (=excl)
    __shared__ int bme[NB];                   // base - excl
    __shared__ int wt8[8];                    // wave scan partials
    const int tid = threadIdx.x;
    const int lane = tid & 63, wvx = tid >> 6;   // 4 waves
    for (int j = tid; j < NB; j += 256) cnt[j] = 0;
    __syncthreads();
    const long long b0 = (long long)blockIdx.x * CHUNK;
    const int valid = (int)min((long long)CHUNK, (long long)NE - b0);
    #pragma unroll
    for (int k = 0; k < CHUNK / 256; ++k) {
        int idx = k * 256 + tid;
        if (idx < valid) {
            long long e = b0 + idx;
            int d = dst[e];
            int b = d >> 8;
            la[idx] = src[e] | ((d & 255) << 17);
            lw[idx] = f2hb(ew[e]);
            lb[idx] = (unsigned short)b;
            atomicAdd(&cnt[b], 1);
        }
    }
    __syncthreads();
    // exclusive scan of 512 slots (NB=391 live) via per-wave shfl scans
    int v0 = (tid < NB) ? cnt[tid] : 0;
    int v1 = (tid + 256 < NB) ? cnt[tid + 256] : 0;
    int i0 = v0, i1 = v1;
    #pragma unroll
    for (int off = 1; off < 64; off <<= 1) {
        int t0 = __shfl_up(i0, off, 64);
        int t1 = __shfl_up(i1, off, 64);
        if (lane >= off) { i0 += t0; i1 += t1; }
    }
    if (lane == 63) { wt8[wvx] = i0; wt8[4 + wvx] = i1; }
    __syncthreads();
    int off0 = 0, off1 = 0;
    #pragma unroll
    for (int j = 0; j < 8; ++j) {
        int wt = wt8[j];
        if (j < wvx) off0 += wt;
        if (j < 4 + wvx) off1 += wt;
    }
    const int excl0 = off0 + i0 - v0;
    const int excl1 = off1 + i1 - v1;
    if (tid < NB) {
        int bb = v0 ? atomicAdd(&gcur[tid], v0) : 0;
        bme[tid] = bb - excl0;
        cnt[tid] = excl0;
    }
    if (tid + 256 < NB) {
        int bb = v1 ? atomicAdd(&gcur[tid + 256], v1) : 0;
        bme[tid + 256] = bb - excl1;
        cnt[tid + 256] = excl1;
    }
    __syncthreads();
    // placement: sorted position per record
    #pragma unroll
    for (int k = 0; k < CHUNK / 256; ++k) {
        int idx = k * 256 + tid;
        if (idx < valid) {
            int sp = atomicAdd(&cnt[lb[idx]], 1);
            sidx[sp] = (unsigned short)idx;
        }
    }
    __syncthreads();
    // emission in bucket order: consecutive lanes -> consecutive addresses per run
    #pragma unroll
    for (int k = 0; k < CHUNK / 256; ++k) {
        int sp = k * 256 + tid;
        if (sp < valid) {
            int idx = sidx[sp];
            int b = lb[idx];
            int go = bme[b] + sp;
            rec_a[go] = la[idx];
            rec_w[go] = lw[idx];
        }
    }
}

// -------- split s1: 2 blocks/bucket, LDS partials -> clustered global atomics ----
__global__ __launch_bounds__(512) void k_s1(const int* __restrict__ gcur,
                                            const int* __restrict__ rec_a,
                                            const unsigned short* __restrict__ rec_w,
                                            const float* __restrict__ x,
                                            float* __restrict__ sxf) {
    __shared__ float loc[NPB];
    if (threadIdx.x < NPB) loc[threadIdx.x] = 0.f;
    __syncthreads();
    const int wid = blockIdx.x;
    const int b = wid >> 1, j = wid & 1;
    const int beg = b * CAP, cnt = gcur[b] - beg;
    const int half = (cnt + 1) >> 1;
    const int s0 = beg + j * half;
    const int s1e = beg + min(cnt, j * half + half);
    for (int t = s0 + threadIdx.x; t < s1e; t += 512) {
        const int a = rec_a[t];
        const float w = h2f(rec_w[t]);
        atomicAdd(&loc[a >> 17], w * x[a & SRCM]);
    }
    __syncthreads();
    const int i = b * NPB + threadIdx.x;
    if (threadIdx.x < NPB && i < NN) {
        float v = loc[threadIdx.x];
        if (v != 0.f) atomicAdd(&sxf[2 * i], v);
    }
}

// -------- pack: per-window LDS image (3 u16 planes), coalesced dump ----
__global__ __launch_bounds__(512) void k_pack(const int* __restrict__ gcur,
                                              const int* __restrict__ rec_a,
                                              const unsigned short* __restrict__ rec_w,
                                              const float2* __restrict__ sx,
                                              unsigned short* __restrict__ rec2s,
                                              unsigned short* __restrict__ rec2x,
                                              unsigned short* __restrict__ rec2f,
                                              int* __restrict__ noff,
                                              unsigned char* __restrict__ ngrp) {
    __shared__ int4 imgq[3 * CAPW / 8];       // 30720 B (3 planes x CAPW u16)
    __shared__ int hist[128];
    __shared__ int exclp[128];
    __shared__ int cur[128];
    __shared__ int wt2[2];
    unsigned short* img = (unsigned short*)imgq;
    unsigned short* ws_img = img;
    unsigned short* wx_img = img + CAPW;
    unsigned short* wf_img = img + 2 * CAPW;
    const int tid = threadIdx.x;
    const int lane = tid & 63, wv = tid >> 6;
    const int wid = blockIdx.x;
    const int b = wid >> 1, h = wid & 1;
    for (int j = tid; j < 3 * CAPW / 8; j += 512) imgq[j] = (int4){0, 0, 0, 0};
    if (tid < 128) hist[tid] = 0;
    __syncthreads();
    const int beg = b * CAP;
    const int cnt = gcur[b] - beg;
    // histogram of our half from rec_a (int4 loads; slice stays L2-hot for pass2)
    {
        const int4* a4 = (const int4*)(rec_a + beg);
        const int n4 = cnt >> 2;
        for (int t = tid; t < n4; t += 512) {
            int4 q = a4[t];
            int d0 = q.x >> 17, d1 = q.y >> 17, d2 = q.z >> 17, d3 = q.w >> 17;
            if ((d0 >> 7) == h) atomicAdd(&hist[d0 & 127], 1);
            if ((d1 >> 7) == h) atomicAdd(&hist[d1 & 127], 1);
            if ((d2 >> 7) == h) atomicAdd(&hist[d2 & 127], 1);
            if ((d3 >> 7) == h) atomicAdd(&hist[d3 & 127], 1);
        }
        for (int t = (n4 << 2) + tid; t < cnt; t += 512) {
            int dl = rec_a[beg + t] >> 17;
            if ((dl >> 7) == h) atomicAdd(&hist[dl & 127], 1);
        }
    }
    __syncthreads();
    // padded exclusive scan over 128 bins (waves 0-1 live)
    int pc = 0, incl = 0;
    if (tid < 128) { pc = (hist[tid] + 7) & ~7; incl = pc; }
    #pragma unroll
    for (int off = 1; off < 64; off <<= 1) {
        int tt = __shfl_up(incl, off, 64);
        if (lane >= off) incl += tt;
    }
    if (tid < 128 && lane == 63) wt2[wv] = incl;
    __syncthreads();
    if (tid < 128) {
        int e0 = ((tid >= 64) ? wt2[0] : 0) + incl - pc;
        exclp[tid] = e0;
        cur[tid] = e0;
        const int node = wid * MNP + tid;
        noff[node] = wid * CAPW + e0;         // absolute slot offset (mult of 8)
        ngrp[node] = (unsigned char)(pc >> 3);
    }
    __syncthreads();
    // pass2: stream rec SoA (4 records/iter), gather sx, scatter into LDS planes
#define PREC(AA, WW) {                                                  \
        const int dl_ = (AA) >> 17;                                     \
        if ((dl_ >> 7) == h) {                                          \
            const float w_ = h2f(WW);                                   \
            const float2 v_ = sx[(AA) & SRCM];                          \
            int gs_ = atomicAdd(&cur[dl_ & 127], 1);                    \
            ws_img[gs_] = f2hb(w_ * v_.x);                              \
            wx_img[gs_] = f2hb(w_ * v_.y);                              \
            wf_img[gs_] = (unsigned short)(WW);                         \
        } }
    {
        const int4* a4 = (const int4*)(rec_a + beg);
        const ushort4* w4 = (const ushort4*)(rec_w + beg);
        const int n4 = cnt >> 2;
        for (int t = tid; t < n4; t += 512) {
            int4 qa = a4[t];
            ushort4 qw = w4[t];
            PREC(qa.x, qw.x)
            PREC(qa.y, qw.y)
            PREC(qa.z, qw.z)
            PREC(qa.w, qw.w)
        }
        for (int t = (n4 << 2) + tid; t < cnt; t += 512) {
            PREC(rec_a[beg + t], rec_w[beg + t])
        }
    }
#undef PREC
    __syncthreads();
    // coalesced dump: 3 x 10240 B per window
    {
        const size_t pb = (size_t)wid * (CAPW / 8);   // int4 index into plane
        int4* d0 = (int4*)rec2s + pb;
        int4* d1 = (int4*)rec2x + pb;
        int4* d2 = (int4*)rec2f + pb;
        for (int j = tid; j < CAPW / 8; j += 512) d0[j] = imgq[j];
        for (int j = tid; j < CAPW / 8; j += 512) d1[j] = imgq[CAPW / 8 + j];
        for (int j = tid; j < CAPW / 8; j += 512) d2[j] = imgq[2 * (CAPW / 8) + j];
    }
}

// -------- mega: branchless pair stream (4-deep, 3-plane) + MFMA --------
// Writes p and out = rv + b3 (k_out atomically adds the aggregation term).
__global__ __launch_bounds__(512) void k_mega(
        const int* __restrict__ noff, const unsigned char* __restrict__ ngrp,
        const unsigned short* __restrict__ rec2s,
        const unsigned short* __restrict__ rec2x,
        const unsigned short* __restrict__ rec2f,
        const float2* __restrict__ sx,
        const float* __restrict__ W1_rel, const float* __restrict__ W1_root,
        const float* __restrict__ b1,
        const float* __restrict__ W2_rel, const float* __restrict__ b2,
        const float* __restrict__ W2_root,
        const float* __restrict__ W3_rel, const float* __restrict__ W3_root,
        const float* __restrict__ b3,
        float* __restrict__ p, float* __restrict__ out) {
    __shared__ _Float16 aggh[MNP * AP];       // 18432 B
    __shared__ _Float16 Bt[HID * BPITCH];     // 17408 B
    __shared__ float2 sxl[MNP];               // 1024 B -> 36.9 KB
    const int tid = threadIdx.x;
    const int f = tid & 63;
    const int wv = tid >> 6;                  // 0..7
    const int gi0 = blockIdx.x * MNP;

    for (int j = tid; j < MNP * AP / 2; j += 512) ((int*)aggh)[j] = 0;
    for (int idx = tid; idx < HID * HID; idx += 512) {
        int k = idx >> 6, n = idx & 63;
        Bt[n * BPITCH + k]       = (_Float16)W2_rel[idx];
        Bt[n * BPITCH + HID + k] = (_Float16)W2_root[idx];
    }
    if (tid < MNP) {
        int gi = gi0 + tid;
        sxl[tid] = (gi < NN) ? sx[gi] : make_float2(0.f, 0.f);
    }
    const float w1rf = W1_rel[f], w1tf = W1_root[f], b1ff = b1[f];
    const float b3v = b3[0];
    __syncthreads();

    {
        const int first = gi0 + wv * 16;
        int soff = __builtin_amdgcn_readfirstlane(noff[first]);
        const int4 gvv = *(const int4*)(ngrp + first);
        unsigned ua = __builtin_amdgcn_readfirstlane((unsigned)gvv.x);
        unsigned ub = __builtin_amdgcn_readfirstlane((unsigned)gvv.y);
        unsigned uc = __builtin_amdgcn_readfirstlane((unsigned)gvv.z);
        unsigned ud = __builtin_amdgcn_readfirstlane((unsigned)gvv.w);
        unsigned long long clo = (unsigned long long)ua | ((unsigned long long)ub << 32);
        unsigned long long chi = (unsigned long long)uc | ((unsigned long long)ud << 32);
        #define BSUM(u) (((u) & 255u) + (((u) >> 8) & 255u) + (((u) >> 16) & 255u) + ((u) >> 24))
        const int tg = (int)(BSUM(ua) + BSUM(ub) + BSUM(uc) + BSUM(ud));
        #undef BSUM

        const h2v w1r2 = {(_Float16)w1rf, (_Float16)w1rf};
        const h2v w1t2 = {(_Float16)w1tf, (_Float16)w1tf};
        const h2v b1f2 = {(_Float16)b1ff, (_Float16)b1ff};
        const h2v one2 = {(_Float16)1.f, (_Float16)1.f};
        const h2v zero2 = {(_Float16)0.f, (_Float16)0.f};

        float a0 = 0.f, a1 = 0.f, a2 = 0.f, a3 = 0.f;
        int nrow = wv * 16;
        const int rowend = nrow + 16;
        int grem = (int)(clo & 255); clo = (clo >> 8) | (chi << 56); chi >>= 8;
        while (grem == 0 && nrow + 1 < rowend) {
            ++nrow; grem = (int)(clo & 255);
            clo = (clo >> 8) | (chi << 56); chi >>= 8;
        }

        // plane base pointers in int4 units (8 slots = 16 B per plane per group)
        const int4* ps = (const int4*)rec2s + (soff >> 3);
        const int4* px = (const int4*)rec2x + (soff >> 3);
        const int4* pf = (const int4*)rec2f + (soff >> 3);

        int4 S0, X0, F0, S1, X1, F1, S2, X2, F2, S3, X3, F3;
        if (tg >= 1) { S0 = ps[0]; X0 = px[0]; F0 = pf[0]; }
        if (tg >= 2) { S1 = ps[1]; X1 = px[1]; F1 = pf[1]; }
        if (tg >= 3) { S2 = ps[2]; X2 = px[2]; F2 = pf[2]; }

// branchless pair: 5 VALU for 2 edges across all 64 features
#define PP(SS, XX, FF, AA) {                                 \
        h2v z_ = ash2((unsigned)(FF)) * b1f2;                \
        z_ = ash2((unsigned)(XX)) * w1t2 + z_;               \
        z_ = ash2((unsigned)(SS)) * w1r2 + z_;               \
        z_ = __builtin_elementwise_max(z_, zero2);           \
        AA = __builtin_amdgcn_fdot2(z_, one2, AA, false); }

#define GRP(S, X, F)                                         \
        PP(S.x, X.x, F.x, a0) PP(S.y, X.y, F.y, a1)          \
        PP(S.z, X.z, F.z, a2) PP(S.w, X.w, F.w, a3)

#define BNDRY() {                                                        \
        if (--grem == 0) {                                               \
            aggh[nrow * AP + f] = (_Float16)((a0 + a1) + (a2 + a3));     \
            a0 = a1 = a2 = a3 = 0.f;                                     \
            ++nrow; grem = (int)(clo & 255);                             \
            clo = (clo >> 8) | (chi << 56); chi >>= 8;                   \
            while (grem == 0 && nrow + 1 < rowend) {                     \
                ++nrow; grem = (int)(clo & 255);                         \
                clo = (clo >> 8) | (chi << 56); chi >>= 8;               \
            }                                                            \
        } }

        int t = 0;
        // steady state: 4 groups in flight (overrun reads land in ws slack)
        while (t + 4 <= tg) {
            S3 = ps[t + 3]; X3 = px[t + 3]; F3 = pf[t + 3];
            GRP(S0, X0, F0) BNDRY(); ++t;
            S0 = ps[t + 3]; X0 = px[t + 3]; F0 = pf[t + 3];
            GRP(S1, X1, F1) BNDRY(); ++t;
            S1 = ps[t + 3]; X1 = px[t + 3]; F1 = pf[t + 3];
            GRP(S2, X2, F2) BNDRY(); ++t;
            S2 = ps[t + 3]; X2 = px[t + 3]; F2 = pf[t + 3];
            GRP(S3, X3, F3) BNDRY(); ++t;
        }
        if (t < tg) {
            GRP(S0, X0, F0) BNDRY(); ++t;
            if (t < tg) {
                GRP(S1, X1, F1) BNDRY(); ++t;
                if (t < tg) {
                    GRP(S2, X2, F2) BNDRY(); ++t;
                }
            }
        }
#undef PP
#undef GRP
#undef BNDRY
    }
    __syncthreads();

    const int m16 = tid & 15;
    const int quad = (tid & 63) >> 4;
    f32x4 acc[4];
    #pragma unroll
    for (int c_ = 0; c_ < 4; ++c_) acc[c_] = (f32x4){0.f, 0.f, 0.f, 0.f};

    const float2 sm = sxl[wv * 16 + m16];

    #pragma unroll
    for (int kt = 0; kt < 4; ++kt) {
        const int kk = kt * 32;
        half8 af;
        if (kt < 2) {
            af = *(const half8*)&aggh[(wv * 16 + m16) * AP + kk + quad * 8];
        } else {
            const int fk0 = (kt - 2) * 32 + quad * 8;
            #pragma unroll
            for (int j = 0; j < 8; ++j) {
                const float wr = W1_rel[fk0 + j], wt = W1_root[fk0 + j], bb = b1[fk0 + j];
                af[j] = (_Float16)fmaxf(0.f, fmaf(sm.x, wr, fmaf(sm.y, wt, bb)));
            }
        }
        #pragma unroll
        for (int ct = 0; ct < 4; ++ct) {
            const half8 bfrag = *(const half8*)&Bt[(ct * 16 + m16) * BPITCH + kk + quad * 8];
            acc[ct] = __builtin_amdgcn_mfma_f32_16x16x32_f16(af, bfrag, acc[ct], 0, 0, 0);
        }
    }

    float b2c[4], w3rc[4], w3tc[4];
    #pragma unroll
    for (int ct = 0; ct < 4; ++ct) {
        const int col = ct * 16 + m16;
        b2c[ct] = b2[col]; w3rc[ct] = W3_rel[col]; w3tc[ct] = W3_root[col];
    }
    float pv[4] = {0.f, 0.f, 0.f, 0.f}, rv[4] = {0.f, 0.f, 0.f, 0.f};
    #pragma unroll
    for (int ct = 0; ct < 4; ++ct) {
        #pragma unroll
        for (int reg = 0; reg < 4; ++reg) {
            const float h2_ = fmaxf(0.f, acc[ct][reg] + b2c[ct]);
            pv[reg] = fmaf(h2_, w3rc[ct], pv[reg]);
            rv[reg] = fmaf(h2_, w3tc[ct], rv[reg]);
        }
    }
    #pragma unroll
    for (int reg = 0; reg < 4; ++reg) {
        #pragma unroll
        for (int msk = 1; msk < 16; msk <<= 1) {
            pv[reg] += __shfl_xor(pv[reg], msk, 64);
            rv[reg] += __shfl_xor(rv[reg], msk, 64);
        }
    }
    if (m16 == 0) {
        #pragma unroll
        for (int reg = 0; reg < 4; ++reg) {
            const int gi = gi0 + wv * 16 + quad * 4 + reg;
            if (gi < NN) { p[gi] = pv[reg]; out[gi] = rv[reg] + b3v; }
        }
    }
}

// -------- split out: 2 blocks/bucket; out += seg_sum(w * p[src]) via atomics ----
__global__ __launch_bounds__(512) void k_out(const int* __restrict__ gcur,
                                             const int* __restrict__ rec_a,
                                             const unsigned short* __restrict__ rec_w,
                                             const float* __restrict__ pp,
                                             float* __restrict__ out) {
    __shared__ float loc[NPB];
    if (threadIdx.x < NPB) loc[threadIdx.x] = 0.f;
    __syncthreads();
    const int wid = blockIdx.x;
    const int b = wid >> 1, j = wid & 1;
    const int beg = b * CAP, cnt = gcur[b] - beg;
    const int half = (cnt + 1) >> 1;
    const int s0 = beg + j * half;
    const int s1e = beg + min(cnt, j * half + half);
    for (int t = s0 + threadIdx.x; t < s1e; t += 512) {
        const int a = rec_a[t];
        const float w = h2f(rec_w[t]);
        atomicAdd(&loc[a >> 17], w * pp[a & SRCM]);
    }
    __syncthreads();
    const int i = b * NPB + threadIdx.x;
    if (threadIdx.x < NPB && i < NN) {
        float v = loc[threadIdx.x];
        if (v != 0.f) atomicAdd(&out[i], v);
    }
}

extern "C" void kernel_launch(void* const* d_in, const int* in_sizes, int n_in,
                              void* d_out, int out_size, void* d_ws, size_t ws_size,
                              hipStream_t stream) {
    const float* x       = (const float*)d_in[0];
    const int*   ei      = (const int*)  d_in[1];
    const float* ew      = (const float*)d_in[2];
    const float* W1_rel  = (const float*)d_in[3];
    const float* b1      = (const float*)d_in[4];
    const float* W1_root = (const float*)d_in[5];
    const float* W2_rel  = (const float*)d_in[6];
    const float* b2      = (const float*)d_in[7];
    const float* W2_root = (const float*)d_in[8];
    const float* W3_rel  = (const float*)d_in[9];
    const float* b3      = (const float*)d_in[10];
    const float* W3_root = (const float*)d_in[11];

    const int* src = ei;
    const int* dst = ei + NE;

    // workspace layout (~48 MB of the ~268 MB workspace)
    const size_t REC_SLOTS = (size_t)NB * CAP;            // 3.60M slots
    const size_t PLANE     = (size_t)NMW * CAPW;          // 4.00M u16 slots / plane
    int*            rec_a = (int*)d_ws;                   // 14.4 MB
    unsigned short* rec_w = (unsigned short*)(rec_a + REC_SLOTS); // 7.2 MB
    float2*         sx    = (float2*)(rec_w + REC_SLOTS); // 800 KB
    float*          p     = (float*)(sx + NN);            // 400 KB
    int*            noff  = (int*)(p + NN);               // NNP*4
    unsigned char*  ngrp  = (unsigned char*)(noff + NNP); // NNP
    int*            gcur  = (int*)(ngrp + NNP);           // NB*4
    char*           tail  = (char*)(gcur + NB);
    size_t          off   = ((size_t)(tail - (char*)d_ws) + 15) & ~(size_t)15;
    unsigned short* rec2s = (unsigned short*)((char*)d_ws + off);   // 8.0 MB
    unsigned short* rec2x = rec2s + PLANE;                          // 8.0 MB
    unsigned short* rec2f = rec2x + PLANE;                          // 8.0 MB

    k_init<<<(NN + 511) / 512, 512, 0, stream>>>(x, sx, gcur);
    k_scatter<<<NCH, 256, 0, stream>>>(src, dst, ew, gcur, rec_a, rec_w);
    k_s1<<<2 * NB, 512, 0, stream>>>(gcur, rec_a, rec_w, x, (float*)sx);
    k_pack<<<NMW, 512, 0, stream>>>(gcur, rec_a, rec_w, sx,
                                    rec2s, rec2x, rec2f, noff, ngrp);
    k_mega<<<NMW, 512, 0, stream>>>(noff, ngrp, rec2s, rec2x, rec2f, sx,
                                    W1_rel, W1_root, b1,
                                    W2_rel, b2, W2_root,
                                    W3_rel, W3_root, b3, p, (float*)d_out);
    k_out<<<2 * NB, 512, 0, stream>>>(gcur, rec_a, rec_w, p, (float*)d_out);
}

// Round 10
// 237.260 us; speedup vs baseline: 6.3964x; 1.0435x over previous
//
#include <hip/hip_runtime.h>

#define NN 100000
#define NE 3200000
#define HID 64
#define NPB 256                         // nodes per bucket (dl = dst & 255)
#define NB  ((NN + NPB - 1) / NPB)      // 391 buckets
#define NNP (NB * NPB)                  // 100096 padded node slots
#define CAP 9216                        // bucket capacity: mean 8192, +11 sigma
#define MNP 128                         // nodes per window
#define NMW (2 * NB)                    // 782 windows
#define CAPW 5120                       // padded slots per window: mean ~4544, +8.7 sigma
#define CHUNK 4096                      // edges per scatter workgroup (R5-proven)
#define NCH ((NE + CHUNK - 1) / CHUNK)  // 782 chunks
#define AP 72                           // f16 agg row pitch in halfs (144 B)
#define BPITCH 136                      // f16 Bt row pitch in halfs (272 B)
#define SRCM 0x1FFFF                    // src mask (17 bits; NN < 2^17)

typedef _Float16 half8 __attribute__((ext_vector_type(8)));
typedef _Float16 h2v   __attribute__((ext_vector_type(2)));
typedef float f32x4 __attribute__((ext_vector_type(4)));

__device__ __forceinline__ unsigned short f2hb(float v) {
    _Float16 h = (_Float16)v;
    unsigned short s;
    __builtin_memcpy(&s, &h, 2);
    return s;
}
__device__ __forceinline__ float h2f(unsigned int u) {
    unsigned short s = (unsigned short)u;
    _Float16 h;
    __builtin_memcpy(&h, &s, 2);
    return (float)h;
}
__device__ __forceinline__ h2v ash2(unsigned int u) {
    h2v r;
    __builtin_memcpy(&r, &u, 4);
    return r;
}

// -------- init: sx = (0, x) so split-s1 merges via atomics; bucket cursors --------
__global__ __launch_bounds__(512) void k_init(const float* __restrict__ x,
                                              float2* __restrict__ sx,
                                              int* __restrict__ gcur) {
    const int i = blockIdx.x * 512 + threadIdx.x;
    if (i < NN) sx[i] = make_float2(0.f, x[i]);
    if (blockIdx.x == 0 && threadIdx.x < NB) gcur[threadIdx.x] = threadIdx.x * CAP;
}

// -------- scatter: in-LDS counting sort -> bucket-grouped SoA emission ----
// 512 threads (8 waves): same LDS/work as R9, 2x the latency-hiding waves.
__global__ __launch_bounds__(512) void k_scatter(const int* __restrict__ src,
                                                 const int* __restrict__ dst,
                                                 const float* __restrict__ ew,
                                                 int* __restrict__ gcur,
                                                 int* __restrict__ rec_a,
                                                 unsigned short* __restrict__ rec_w) {
    __shared__ int la[CHUNK];                 // 16 KB
    __shared__ unsigned short lw[CHUNK];      // 8 KB
    __shared__ unsigned short lb[CHUNK];      // 8 KB  (bucket id per record)
    __shared__ unsigned short sidx[CHUNK];    // 8 KB  (sorted-order -> record idx)
    __shared__ int cnt[NB];                   // counts, then cursor (=excl)
    __shared__ int bme[NB];                   // base - excl
    __shared__ int wt8[8];                    // wave scan partials
    const int tid = threadIdx.x;
    const int lane = tid & 63, wvx = tid >> 6;   // 8 waves
    for (int j = tid; j < NB; j += 512) cnt[j] = 0;
    __syncthreads();
    const long long b0 = (long long)blockIdx.x * CHUNK;
    const int valid = (int)min((long long)CHUNK, (long long)NE - b0);
    #pragma unroll
    for (int k = 0; k < CHUNK / 512; ++k) {
        int idx = k * 512 + tid;
        if (idx < valid) {
            long long e = b0 + idx;
            int d = dst[e];
            int b = d >> 8;
            la[idx] = src[e] | ((d & 255) << 17);
            lw[idx] = f2hb(ew[e]);
            lb[idx] = (unsigned short)b;
            atomicAdd(&cnt[b], 1);
        }
    }
    __syncthreads();
    // exclusive scan over NB=391 slots: one value per thread, 8-wave shfl scan
    const int v = (tid < NB) ? cnt[tid] : 0;
    int incl = v;
    #pragma unroll
    for (int off = 1; off < 64; off <<= 1) {
        int t0 = __shfl_up(incl, off, 64);
        if (lane >= off) incl += t0;
    }
    if (lane == 63) wt8[wvx] = incl;
    __syncthreads();
    int offs = 0;
    #pragma unroll
    for (int j = 0; j < 8; ++j)
        if (j < wvx) offs += wt8[j];
    const int excl = offs + incl - v;
    if (tid < NB) {
        int bb = v ? atomicAdd(&gcur[tid], v) : 0;
        bme[tid] = bb - excl;
        cnt[tid] = excl;                      // cursor
    }
    __syncthreads();
    // placement: sorted position per record
    #pragma unroll
    for (int k = 0; k < CHUNK / 512; ++k) {
        int idx = k * 512 + tid;
        if (idx < valid) {
            int sp = atomicAdd(&cnt[lb[idx]], 1);
            sidx[sp] = (unsigned short)idx;
        }
    }
    __syncthreads();
    // emission in bucket order: consecutive lanes -> consecutive addresses per run
    #pragma unroll
    for (int k = 0; k < CHUNK / 512; ++k) {
        int sp = k * 512 + tid;
        if (sp < valid) {
            int idx = sidx[sp];
            int b = lb[idx];
            int go = bme[b] + sp;
            rec_a[go] = la[idx];
            rec_w[go] = lw[idx];
        }
    }
}

// -------- split s1: 4 blocks/bucket, LDS partials -> clustered global atomics ----
__global__ __launch_bounds__(512) void k_s1(const int* __restrict__ gcur,
                                            const int* __restrict__ rec_a,
                                            const unsigned short* __restrict__ rec_w,
                                            const float* __restrict__ x,
                                            float* __restrict__ sxf) {
    __shared__ float loc[NPB];
    if (threadIdx.x < NPB) loc[threadIdx.x] = 0.f;
    __syncthreads();
    const int wid = blockIdx.x;
    const int b = wid >> 2, j = wid & 3;
    const int beg = b * CAP, cnt = gcur[b] - beg;
    const int qtr = (cnt + 3) >> 2;
    const int s0 = beg + min(cnt, j * qtr);
    const int s1e = beg + min(cnt, (j + 1) * qtr);
    for (int t = s0 + threadIdx.x; t < s1e; t += 512) {
        const int a = rec_a[t];
        const float w = h2f(rec_w[t]);
        atomicAdd(&loc[a >> 17], w * x[a & SRCM]);
    }
    __syncthreads();
    const int i = b * NPB + threadIdx.x;
    if (threadIdx.x < NPB && i < NN) {
        float v = loc[threadIdx.x];
        if (v != 0.f) atomicAdd(&sxf[2 * i], v);
    }
}

// -------- pack: per-window LDS image (3 u16 planes), coalesced dump ----
__global__ __launch_bounds__(512) void k_pack(const int* __restrict__ gcur,
                                              const int* __restrict__ rec_a,
                                              const unsigned short* __restrict__ rec_w,
                                              const float2* __restrict__ sx,
                                              unsigned short* __restrict__ rec2s,
                                              unsigned short* __restrict__ rec2x,
                                              unsigned short* __restrict__ rec2f,
                                              int* __restrict__ noff,
                                              unsigned char* __restrict__ ngrp) {
    __shared__ int4 imgq[3 * CAPW / 8];       // 30720 B (3 planes x CAPW u16)
    __shared__ int hist[128];
    __shared__ int exclp[128];
    __shared__ int cur[128];
    __shared__ int wt2[2];
    unsigned short* img = (unsigned short*)imgq;
    unsigned short* ws_img = img;
    unsigned short* wx_img = img + CAPW;
    unsigned short* wf_img = img + 2 * CAPW;
    const int tid = threadIdx.x;
    const int lane = tid & 63, wv = tid >> 6;
    const int wid = blockIdx.x;
    const int b = wid >> 1, h = wid & 1;
    for (int j = tid; j < 3 * CAPW / 8; j += 512) imgq[j] = (int4){0, 0, 0, 0};
    if (tid < 128) hist[tid] = 0;
    __syncthreads();
    const int beg = b * CAP;
    const int cnt = gcur[b] - beg;
    // histogram of our half from rec_a (int4 loads; slice stays L2-hot for pass2)
    {
        const int4* a4 = (const int4*)(rec_a + beg);
        const int n4 = cnt >> 2;
        for (int t = tid; t < n4; t += 512) {
            int4 q = a4[t];
            int d0 = q.x >> 17, d1 = q.y >> 17, d2 = q.z >> 17, d3 = q.w >> 17;
            if ((d0 >> 7) == h) atomicAdd(&hist[d0 & 127], 1);
            if ((d1 >> 7) == h) atomicAdd(&hist[d1 & 127], 1);
            if ((d2 >> 7) == h) atomicAdd(&hist[d2 & 127], 1);
            if ((d3 >> 7) == h) atomicAdd(&hist[d3 & 127], 1);
        }
        for (int t = (n4 << 2) + tid; t < cnt; t += 512) {
            int dl = rec_a[beg + t] >> 17;
            if ((dl >> 7) == h) atomicAdd(&hist[dl & 127], 1);
        }
    }
    __syncthreads();
    // padded exclusive scan over 128 bins (waves 0-1 live)
    int pc = 0, incl = 0;
    if (tid < 128) { pc = (hist[tid] + 7) & ~7; incl = pc; }
    #pragma unroll
    for (int off = 1; off < 64; off <<= 1) {
        int tt = __shfl_up(incl, off, 64);
        if (lane >= off) incl += tt;
    }
    if (tid < 128 && lane == 63) wt2[wv] = incl;
    __syncthreads();
    if (tid < 128) {
        int e0 = ((tid >= 64) ? wt2[0] : 0) + incl - pc;
        exclp[tid] = e0;
        cur[tid] = e0;
        const int node = wid * MNP + tid;
        noff[node] = wid * CAPW + e0;         // absolute slot offset (mult of 8)
        ngrp[node] = (unsigned char)(pc >> 3);
    }
    __syncthreads();
    // pass2: stream rec SoA (4 records/iter), gather sx, scatter into LDS planes
#define PREC(AA, WW) {                                                  \
        const int dl_ = (AA) >> 17;                                     \
        if ((dl_ >> 7) == h) {                                          \
            const float w_ = h2f(WW);                                   \
            const float2 v_ = sx[(AA) & SRCM];                          \
            int gs_ = atomicAdd(&cur[dl_ & 127], 1);                    \
            ws_img[gs_] = f2hb(w_ * v_.x);                              \
            wx_img[gs_] = f2hb(w_ * v_.y);                              \
            wf_img[gs_] = (unsigned short)(WW);                         \
        } }
    {
        const int4* a4 = (const int4*)(rec_a + beg);
        const ushort4* w4 = (const ushort4*)(rec_w + beg);
        const int n4 = cnt >> 2;
        for (int t = tid; t < n4; t += 512) {
            int4 qa = a4[t];
            ushort4 qw = w4[t];
            PREC(qa.x, qw.x)
            PREC(qa.y, qw.y)
            PREC(qa.z, qw.z)
            PREC(qa.w, qw.w)
        }
        for (int t = (n4 << 2) + tid; t < cnt; t += 512) {
            PREC(rec_a[beg + t], rec_w[beg + t])
        }
    }
#undef PREC
    __syncthreads();
    // coalesced dump: 3 x 10240 B per window
    {
        const size_t pb = (size_t)wid * (CAPW / 8);   // int4 index into plane
        int4* d0 = (int4*)rec2s + pb;
        int4* d1 = (int4*)rec2x + pb;
        int4* d2 = (int4*)rec2f + pb;
        for (int j = tid; j < CAPW / 8; j += 512) d0[j] = imgq[j];
        for (int j = tid; j < CAPW / 8; j += 512) d1[j] = imgq[CAPW / 8 + j];
        for (int j = tid; j < CAPW / 8; j += 512) d2[j] = imgq[2 * (CAPW / 8) + j];
    }
}

// -------- mega: branchless pair stream (4-deep, 3-plane) + MFMA --------
// Writes p and out = rv + b3 (k_out atomically adds the aggregation term).
__global__ __launch_bounds__(512) void k_mega(
        const int* __restrict__ noff, const unsigned char* __restrict__ ngrp,
        const unsigned short* __restrict__ rec2s,
        const unsigned short* __restrict__ rec2x,
        const unsigned short* __restrict__ rec2f,
        const float2* __restrict__ sx,
        const float* __restrict__ W1_rel, const float* __restrict__ W1_root,
        const float* __restrict__ b1,
        const float* __restrict__ W2_rel, const float* __restrict__ b2,
        const float* __restrict__ W2_root,
        const float* __restrict__ W3_rel, const float* __restrict__ W3_root,
        const float* __restrict__ b3,
        float* __restrict__ p, float* __restrict__ out) {
    __shared__ _Float16 aggh[MNP * AP];       // 18432 B
    __shared__ _Float16 Bt[HID * BPITCH];     // 17408 B
    __shared__ float2 sxl[MNP];               // 1024 B -> 36.9 KB
    const int tid = threadIdx.x;
    const int f = tid & 63;
    const int wv = tid >> 6;                  // 0..7
    const int gi0 = blockIdx.x * MNP;

    for (int j = tid; j < MNP * AP / 2; j += 512) ((int*)aggh)[j] = 0;
    for (int idx = tid; idx < HID * HID; idx += 512) {
        int k = idx >> 6, n = idx & 63;
        Bt[n * BPITCH + k]       = (_Float16)W2_rel[idx];
        Bt[n * BPITCH + HID + k] = (_Float16)W2_root[idx];
    }
    if (tid < MNP) {
        int gi = gi0 + tid;
        sxl[tid] = (gi < NN) ? sx[gi] : make_float2(0.f, 0.f);
    }
    const float w1rf = W1_rel[f], w1tf = W1_root[f], b1ff = b1[f];
    const float b3v = b3[0];
    __syncthreads();

    {
        const int first = gi0 + wv * 16;
        int soff = __builtin_amdgcn_readfirstlane(noff[first]);
        const int4 gvv = *(const int4*)(ngrp + first);
        unsigned ua = __builtin_amdgcn_readfirstlane((unsigned)gvv.x);
        unsigned ub = __builtin_amdgcn_readfirstlane((unsigned)gvv.y);
        unsigned uc = __builtin_amdgcn_readfirstlane((unsigned)gvv.z);
        unsigned ud = __builtin_amdgcn_readfirstlane((unsigned)gvv.w);
        unsigned long long clo = (unsigned long long)ua | ((unsigned long long)ub << 32);
        unsigned long long chi = (unsigned long long)uc | ((unsigned long long)ud << 32);
        #define BSUM(u) (((u) & 255u) + (((u) >> 8) & 255u) + (((u) >> 16) & 255u) + ((u) >> 24))
        const int tg = (int)(BSUM(ua) + BSUM(ub) + BSUM(uc) + BSUM(ud));
        #undef BSUM

        const h2v w1r2 = {(_Float16)w1rf, (_Float16)w1rf};
        const h2v w1t2 = {(_Float16)w1tf, (_Float16)w1tf};
        const h2v b1f2 = {(_Float16)b1ff, (_Float16)b1ff};
        const h2v one2 = {(_Float16)1.f, (_Float16)1.f};
        const h2v zero2 = {(_Float16)0.f, (_Float16)0.f};

        float a0 = 0.f, a1 = 0.f, a2 = 0.f, a3 = 0.f;
        int nrow = wv * 16;
        const int rowend = nrow + 16;
        int grem = (int)(clo & 255); clo = (clo >> 8) | (chi << 56); chi >>= 8;
        while (grem == 0 && nrow + 1 < rowend) {
            ++nrow; grem = (int)(clo & 255);
            clo = (clo >> 8) | (chi << 56); chi >>= 8;
        }

        // plane base pointers in int4 units (8 slots = 16 B per plane per group)
        const int4* ps = (const int4*)rec2s + (soff >> 3);
        const int4* px = (const int4*)rec2x + (soff >> 3);
        const int4* pf = (const int4*)rec2f + (soff >> 3);

        int4 S0, X0, F0, S1, X1, F1, S2, X2, F2, S3, X3, F3;
        if (tg >= 1) { S0 = ps[0]; X0 = px[0]; F0 = pf[0]; }
        if (tg >= 2) { S1 = ps[1]; X1 = px[1]; F1 = pf[1]; }
        if (tg >= 3) { S2 = ps[2]; X2 = px[2]; F2 = pf[2]; }

// branchless pair: 5 VALU for 2 edges across all 64 features
#define PP(SS, XX, FF, AA) {                                 \
        h2v z_ = ash2((unsigned)(FF)) * b1f2;                \
        z_ = ash2((unsigned)(XX)) * w1t2 + z_;               \
        z_ = ash2((unsigned)(SS)) * w1r2 + z_;               \
        z_ = __builtin_elementwise_max(z_, zero2);           \
        AA = __builtin_amdgcn_fdot2(z_, one2, AA, false); }

#define GRP(S, X, F)                                         \
        PP(S.x, X.x, F.x, a0) PP(S.y, X.y, F.y, a1)          \
        PP(S.z, X.z, F.z, a2) PP(S.w, X.w, F.w, a3)

#define BNDRY() {                                                        \
        if (--grem == 0) {                                               \
            aggh[nrow * AP + f] = (_Float16)((a0 + a1) + (a2 + a3));     \
            a0 = a1 = a2 = a3 = 0.f;                                     \
            ++nrow; grem = (int)(clo & 255);                             \
            clo = (clo >> 8) | (chi << 56); chi >>= 8;                   \
            while (grem == 0 && nrow + 1 < rowend) {                     \
                ++nrow; grem = (int)(clo & 255);                         \
                clo = (clo >> 8) | (chi << 56); chi >>= 8;               \
            }                                                            \
        } }

        int t = 0;
        // steady state: 4 groups in flight (overrun reads land in plane slack)
        while (t + 4 <= tg) {
            S3 = ps[t + 3]; X3 = px[t + 3]; F3 = pf[t + 3];
            GRP(S0, X0, F0) BNDRY(); ++t;
            S0 = ps[t + 3]; X0 = px[t + 3]; F0 = pf[t + 3];
            GRP(S1, X1, F1) BNDRY(); ++t;
            S1 = ps[t + 3]; X1 = px[t + 3]; F1 = pf[t + 3];
            GRP(S2, X2, F2) BNDRY(); ++t;
            S2 = ps[t + 3]; X2 = px[t + 3]; F2 = pf[t + 3];
            GRP(S3, X3, F3) BNDRY(); ++t;
        }
        if (t < tg) {
            GRP(S0, X0, F0) BNDRY(); ++t;
            if (t < tg) {
                GRP(S1, X1, F1) BNDRY(); ++t;
                if (t < tg) {
                    GRP(S2, X2, F2) BNDRY(); ++t;
                }
            }
        }
#undef PP
#undef GRP
#undef BNDRY
    }
    __syncthreads();

    const int m16 = tid & 15;
    const int quad = (tid & 63) >> 4;
    f32x4 acc[4];
    #pragma unroll
    for (int c_ = 0; c_ < 4; ++c_) acc[c_] = (f32x4){0.f, 0.f, 0.f, 0.f};

    const float2 sm = sxl[wv * 16 + m16];

    #pragma unroll
    for (int kt = 0; kt < 4; ++kt) {
        const int kk = kt * 32;
        half8 af;
        if (kt < 2) {
            af = *(const half8*)&aggh[(wv * 16 + m16) * AP + kk + quad * 8];
        } else {
            const int fk0 = (kt - 2) * 32 + quad * 8;
            #pragma unroll
            for (int j = 0; j < 8; ++j) {
                const float wr = W1_rel[fk0 + j], wt = W1_root[fk0 + j], bb = b1[fk0 + j];
                af[j] = (_Float16)fmaxf(0.f, fmaf(sm.x, wr, fmaf(sm.y, wt, bb)));
            }
        }
        #pragma unroll
        for (int ct = 0; ct < 4; ++ct) {
            const half8 bfrag = *(const half8*)&Bt[(ct * 16 + m16) * BPITCH + kk + quad * 8];
            acc[ct] = __builtin_amdgcn_mfma_f32_16x16x32_f16(af, bfrag, acc[ct], 0, 0, 0);
        }
    }

    float b2c[4], w3rc[4], w3tc[4];
    #pragma unroll
    for (int ct = 0; ct < 4; ++ct) {
        const int col = ct * 16 + m16;
        b2c[ct] = b2[col]; w3rc[ct] = W3_rel[col]; w3tc[ct] = W3_root[col];
    }
    float pv[4] = {0.f, 0.f, 0.f, 0.f}, rv[4] = {0.f, 0.f, 0.f, 0.f};
    #pragma unroll
    for (int ct = 0; ct < 4; ++ct) {
        #pragma unroll
        for (int reg = 0; reg < 4; ++reg) {
            const float h2_ = fmaxf(0.f, acc[ct][reg] + b2c[ct]);
            pv[reg] = fmaf(h2_, w3rc[ct], pv[reg]);
            rv[reg] = fmaf(h2_, w3tc[ct], rv[reg]);
        }
    }
    #pragma unroll
    for (int reg = 0; reg < 4; ++reg) {
        #pragma unroll
        for (int msk = 1; msk < 16; msk <<= 1) {
            pv[reg] += __shfl_xor(pv[reg], msk, 64);
            rv[reg] += __shfl_xor(rv[reg], msk, 64);
        }
    }
    if (m16 == 0) {
        #pragma unroll
        for (int reg = 0; reg < 4; ++reg) {
            const int gi = gi0 + wv * 16 + quad * 4 + reg;
            if (gi < NN) { p[gi] = pv[reg]; out[gi] = rv[reg] + b3v; }
        }
    }
}

// -------- split out: 4 blocks/bucket; out += seg_sum(w * p[src]) via atomics ----
__global__ __launch_bounds__(512) void k_out(const int* __restrict__ gcur,
                                             const int* __restrict__ rec_a,
                                             const unsigned short* __restrict__ rec_w,
                                             const float* __restrict__ pp,
                                             float* __restrict__ out) {
    __shared__ float loc[NPB];
    if (threadIdx.x < NPB) loc[threadIdx.x] = 0.f;
    __syncthreads();
    const int wid = blockIdx.x;
    const int b = wid >> 2, j = wid & 3;
    const int beg = b * CAP, cnt = gcur[b] - beg;
    const int qtr = (cnt + 3) >> 2;
    const int s0 = beg + min(cnt, j * qtr);
    const int s1e = beg + min(cnt, (j + 1) * qtr);
    for (int t = s0 + threadIdx.x; t < s1e; t += 512) {
        const int a = rec_a[t];
        const float w = h2f(rec_w[t]);
        atomicAdd(&loc[a >> 17], w * pp[a & SRCM]);
    }
    __syncthreads();
    const int i = b * NPB + threadIdx.x;
    if (threadIdx.x < NPB && i < NN) {
        float v = loc[threadIdx.x];
        if (v != 0.f) atomicAdd(&out[i], v);
    }
}

extern "C" void kernel_launch(void* const* d_in, const int* in_sizes, int n_in,
                              void* d_out, int out_size, void* d_ws, size_t ws_size,
                              hipStream_t stream) {
    const float* x       = (const float*)d_in[0];
    const int*   ei      = (const int*)  d_in[1];
    const float* ew      = (const float*)d_in[2];
    const float* W1_rel  = (const float*)d_in[3];
    const float* b1      = (const float*)d_in[4];
    const float* W1_root = (const float*)d_in[5];
    const float* W2_rel  = (const float*)d_in[6];
    const float* b2      = (const float*)d_in[7];
    const float* W2_root = (const float*)d_in[8];
    const float* W3_rel  = (const float*)d_in[9];
    const float* b3      = (const float*)d_in[10];
    const float* W3_root = (const float*)d_in[11];

    const int* src = ei;
    const int* dst = ei + NE;

    // workspace layout (~48 MB of the ~268 MB workspace)
    const size_t REC_SLOTS = (size_t)NB * CAP;            // 3.60M slots
    const size_t PLANE     = (size_t)NMW * CAPW;          // 4.00M u16 slots / plane
    int*            rec_a = (int*)d_ws;                   // 14.4 MB
    unsigned short* rec_w = (unsigned short*)(rec_a + REC_SLOTS); // 7.2 MB
    float2*         sx    = (float2*)(rec_w + REC_SLOTS); // 800 KB
    float*          p     = (float*)(sx + NN);            // 400 KB
    int*            noff  = (int*)(p + NN);               // NNP*4
    unsigned char*  ngrp  = (unsigned char*)(noff + NNP); // NNP
    int*            gcur  = (int*)(ngrp + NNP);           // NB*4
    char*           tail  = (char*)(gcur + NB);
    size_t          off   = ((size_t)(tail - (char*)d_ws) + 15) & ~(size_t)15;
    unsigned short* rec2s = (unsigned short*)((char*)d_ws + off);   // 8.0 MB
    unsigned short* rec2x = rec2s + PLANE;                          // 8.0 MB
    unsigned short* rec2f = rec2x + PLANE;                          // 8.0 MB

    k_init<<<(NN + 511) / 512, 512, 0, stream>>>(x, sx, gcur);
    k_scatter<<<NCH, 512, 0, stream>>>(src, dst, ew, gcur, rec_a, rec_w);
    k_s1<<<4 * NB, 512, 0, stream>>>(gcur, rec_a, rec_w, x, (float*)sx);
    k_pack<<<NMW, 512, 0, stream>>>(gcur, rec_a, rec_w, sx,
                                    rec2s, rec2x, rec2f, noff, ngrp);
    k_mega<<<NMW, 512, 0, stream>>>(noff, ngrp, rec2s, rec2x, rec2f, sx,
                                    W1_rel, W1_root, b1,
                                    W2_rel, b2, W2_root,
                                    W3_rel, W3_root, b3, p, (float*)d_out);
    k_out<<<4 * NB, 512, 0, stream>>>(gcur, rec_a, rec_w, p, (float*)d_out);
}

// Round 11
// 234.485 us; speedup vs baseline: 6.4721x; 1.0118x over previous
//
#include <hip/hip_runtime.h>

#define NN 100000
#define NE 3200000
#define HID 64
#define NPB 256                         // nodes per bucket (dl = dst & 255)
#define NB  ((NN + NPB - 1) / NPB)      // 391 buckets
#define NNP (NB * NPB)                  // 100096 padded node slots
#define CAP 9216                        // bucket capacity: mean 8192, +11 sigma
#define MNP 128                         // nodes per pack window
#define NMW (2 * NB)                    // 782 pack windows
#define WNP 64                          // nodes per mega window (R11: occupancy)
#define NW2 (NNP / WNP)                 // 1564 mega windows
#define CAPW 5120                       // padded slots per pack window
#define CHUNK 4096                      // edges per scatter workgroup (R5-proven)
#define NCH ((NE + CHUNK - 1) / CHUNK)  // 782 chunks
#define AP 72                           // f16 agg row pitch in halfs (144 B)
#define BPITCH 136                      // f16 Bt row pitch in halfs (272 B)
#define SRCM 0x1FFFF                    // src mask (17 bits; NN < 2^17)

typedef _Float16 half8 __attribute__((ext_vector_type(8)));
typedef _Float16 h2v   __attribute__((ext_vector_type(2)));
typedef float f32x4 __attribute__((ext_vector_type(4)));

__device__ __forceinline__ unsigned short f2hb(float v) {
    _Float16 h = (_Float16)v;
    unsigned short s;
    __builtin_memcpy(&s, &h, 2);
    return s;
}
__device__ __forceinline__ float h2f(unsigned int u) {
    unsigned short s = (unsigned short)u;
    _Float16 h;
    __builtin_memcpy(&h, &s, 2);
    return (float)h;
}
__device__ __forceinline__ h2v ash2(unsigned int u) {
    h2v r;
    __builtin_memcpy(&r, &u, 4);
    return r;
}

// -------- init: sx = (0, x) so split-s1 merges via atomics; bucket cursors --------
__global__ __launch_bounds__(512) void k_init(const float* __restrict__ x,
                                              float2* __restrict__ sx,
                                              int* __restrict__ gcur) {
    const int i = blockIdx.x * 512 + threadIdx.x;
    if (i < NN) sx[i] = make_float2(0.f, x[i]);
    if (blockIdx.x == 0 && threadIdx.x < NB) gcur[threadIdx.x] = threadIdx.x * CAP;
}

// -------- scatter: in-LDS counting sort -> bucket-grouped SoA emission ----
__global__ __launch_bounds__(512) void k_scatter(const int* __restrict__ src,
                                                 const int* __restrict__ dst,
                                                 const float* __restrict__ ew,
                                                 int* __restrict__ gcur,
                                                 int* __restrict__ rec_a,
                                                 unsigned short* __restrict__ rec_w) {
    __shared__ int la[CHUNK];                 // 16 KB
    __shared__ unsigned short lw[CHUNK];      // 8 KB
    __shared__ unsigned short lb[CHUNK];      // 8 KB  (bucket id per record)
    __shared__ unsigned short sidx[CHUNK];    // 8 KB  (sorted-order -> record idx)
    __shared__ int cnt[NB];                   // counts, then cursor (=excl)
    __shared__ int bme[NB];                   // base - excl
    __shared__ int wt8[8];                    // wave scan partials
    const int tid = threadIdx.x;
    const int lane = tid & 63, wvx = tid >> 6;   // 8 waves
    for (int j = tid; j < NB; j += 512) cnt[j] = 0;
    __syncthreads();
    const long long b0 = (long long)blockIdx.x * CHUNK;
    const int valid = (int)min((long long)CHUNK, (long long)NE - b0);
    #pragma unroll
    for (int k = 0; k < CHUNK / 512; ++k) {
        int idx = k * 512 + tid;
        if (idx < valid) {
            long long e = b0 + idx;
            int d = dst[e];
            int b = d >> 8;
            la[idx] = src[e] | ((d & 255) << 17);
            lw[idx] = f2hb(ew[e]);
            lb[idx] = (unsigned short)b;
            atomicAdd(&cnt[b], 1);
        }
    }
    __syncthreads();
    // exclusive scan over NB=391 slots: one value per thread, 8-wave shfl scan
    const int v = (tid < NB) ? cnt[tid] : 0;
    int incl = v;
    #pragma unroll
    for (int off = 1; off < 64; off <<= 1) {
        int t0 = __shfl_up(incl, off, 64);
        if (lane >= off) incl += t0;
    }
    if (lane == 63) wt8[wvx] = incl;
    __syncthreads();
    int offs = 0;
    #pragma unroll
    for (int j = 0; j < 8; ++j)
        if (j < wvx) offs += wt8[j];
    const int excl = offs + incl - v;
    if (tid < NB) {
        int bb = v ? atomicAdd(&gcur[tid], v) : 0;
        bme[tid] = bb - excl;
        cnt[tid] = excl;                      // cursor
    }
    __syncthreads();
    // placement: sorted position per record
    #pragma unroll
    for (int k = 0; k < CHUNK / 512; ++k) {
        int idx = k * 512 + tid;
        if (idx < valid) {
            int sp = atomicAdd(&cnt[lb[idx]], 1);
            sidx[sp] = (unsigned short)idx;
        }
    }
    __syncthreads();
    // emission in bucket order: consecutive lanes -> consecutive addresses per run
    #pragma unroll
    for (int k = 0; k < CHUNK / 512; ++k) {
        int sp = k * 512 + tid;
        if (sp < valid) {
            int idx = sidx[sp];
            int b = lb[idx];
            int go = bme[b] + sp;
            rec_a[go] = la[idx];
            rec_w[go] = lw[idx];
        }
    }
}

// -------- split s1: 4 blocks/bucket, LDS partials -> clustered global atomics ----
__global__ __launch_bounds__(512) void k_s1(const int* __restrict__ gcur,
                                            const int* __restrict__ rec_a,
                                            const unsigned short* __restrict__ rec_w,
                                            const float* __restrict__ x,
                                            float* __restrict__ sxf) {
    __shared__ float loc[NPB];
    if (threadIdx.x < NPB) loc[threadIdx.x] = 0.f;
    __syncthreads();
    const int wid = blockIdx.x;
    const int b = wid >> 2, j = wid & 3;
    const int beg = b * CAP, cnt = gcur[b] - beg;
    const int qtr = (cnt + 3) >> 2;
    const int s0 = beg + min(cnt, j * qtr);
    const int s1e = beg + min(cnt, (j + 1) * qtr);
    for (int t = s0 + threadIdx.x; t < s1e; t += 512) {
        const int a = rec_a[t];
        const float w = h2f(rec_w[t]);
        atomicAdd(&loc[a >> 17], w * x[a & SRCM]);
    }
    __syncthreads();
    const int i = b * NPB + threadIdx.x;
    if (threadIdx.x < NPB && i < NN) {
        float v = loc[threadIdx.x];
        if (v != 0.f) atomicAdd(&sxf[2 * i], v);
    }
}

// -------- pack: per-window LDS image (3 u16 planes), coalesced dump ----
__global__ __launch_bounds__(512) void k_pack(const int* __restrict__ gcur,
                                              const int* __restrict__ rec_a,
                                              const unsigned short* __restrict__ rec_w,
                                              const float2* __restrict__ sx,
                                              unsigned short* __restrict__ rec2s,
                                              unsigned short* __restrict__ rec2x,
                                              unsigned short* __restrict__ rec2f,
                                              int* __restrict__ noff,
                                              unsigned char* __restrict__ ngrp) {
    __shared__ int4 imgq[3 * CAPW / 8];       // 30720 B (3 planes x CAPW u16)
    __shared__ int hist[128];
    __shared__ int exclp[128];
    __shared__ int cur[128];
    __shared__ int wt2[2];
    unsigned short* img = (unsigned short*)imgq;
    unsigned short* ws_img = img;
    unsigned short* wx_img = img + CAPW;
    unsigned short* wf_img = img + 2 * CAPW;
    const int tid = threadIdx.x;
    const int lane = tid & 63, wv = tid >> 6;
    const int wid = blockIdx.x;
    const int b = wid >> 1, h = wid & 1;
    for (int j = tid; j < 3 * CAPW / 8; j += 512) imgq[j] = (int4){0, 0, 0, 0};
    if (tid < 128) hist[tid] = 0;
    __syncthreads();
    const int beg = b * CAP;
    const int cnt = gcur[b] - beg;
    // histogram of our half from rec_a (int4 loads; slice stays L2-hot for pass2)
    {
        const int4* a4 = (const int4*)(rec_a + beg);
        const int n4 = cnt >> 2;
        for (int t = tid; t < n4; t += 512) {
            int4 q = a4[t];
            int d0 = q.x >> 17, d1 = q.y >> 17, d2 = q.z >> 17, d3 = q.w >> 17;
            if ((d0 >> 7) == h) atomicAdd(&hist[d0 & 127], 1);
            if ((d1 >> 7) == h) atomicAdd(&hist[d1 & 127], 1);
            if ((d2 >> 7) == h) atomicAdd(&hist[d2 & 127], 1);
            if ((d3 >> 7) == h) atomicAdd(&hist[d3 & 127], 1);
        }
        for (int t = (n4 << 2) + tid; t < cnt; t += 512) {
            int dl = rec_a[beg + t] >> 17;
            if ((dl >> 7) == h) atomicAdd(&hist[dl & 127], 1);
        }
    }
    __syncthreads();
    // padded exclusive scan over 128 bins (waves 0-1 live)
    int pc = 0, incl = 0;
    if (tid < 128) { pc = (hist[tid] + 7) & ~7; incl = pc; }
    #pragma unroll
    for (int off = 1; off < 64; off <<= 1) {
        int tt = __shfl_up(incl, off, 64);
        if (lane >= off) incl += tt;
    }
    if (tid < 128 && lane == 63) wt2[wv] = incl;
    __syncthreads();
    if (tid < 128) {
        int e0 = ((tid >= 64) ? wt2[0] : 0) + incl - pc;
        exclp[tid] = e0;
        cur[tid] = e0;
        const int node = wid * MNP + tid;
        noff[node] = wid * CAPW + e0;         // absolute slot offset (mult of 8)
        ngrp[node] = (unsigned char)(pc >> 3);
    }
    __syncthreads();
    // pass2: stream rec SoA (4 records/iter), gather sx, scatter into LDS planes
#define PREC(AA, WW) {                                                  \
        const int dl_ = (AA) >> 17;                                     \
        if ((dl_ >> 7) == h) {                                          \
            const float w_ = h2f(WW);                                   \
            const float2 v_ = sx[(AA) & SRCM];                          \
            int gs_ = atomicAdd(&cur[dl_ & 127], 1);                    \
            ws_img[gs_] = f2hb(w_ * v_.x);                              \
            wx_img[gs_] = f2hb(w_ * v_.y);                              \
            wf_img[gs_] = (unsigned short)(WW);                         \
        } }
    {
        const int4* a4 = (const int4*)(rec_a + beg);
        const ushort4* w4 = (const ushort4*)(rec_w + beg);
        const int n4 = cnt >> 2;
        for (int t = tid; t < n4; t += 512) {
            int4 qa = a4[t];
            ushort4 qw = w4[t];
            PREC(qa.x, qw.x)
            PREC(qa.y, qw.y)
            PREC(qa.z, qw.z)
            PREC(qa.w, qw.w)
        }
        for (int t = (n4 << 2) + tid; t < cnt; t += 512) {
            PREC(rec_a[beg + t], rec_w[beg + t])
        }
    }
#undef PREC
    __syncthreads();
    // coalesced dump: 3 x 10240 B per window
    {
        const size_t pb = (size_t)wid * (CAPW / 8);   // int4 index into plane
        int4* d0 = (int4*)rec2s + pb;
        int4* d1 = (int4*)rec2x + pb;
        int4* d2 = (int4*)rec2f + pb;
        for (int j = tid; j < CAPW / 8; j += 512) d0[j] = imgq[j];
        for (int j = tid; j < CAPW / 8; j += 512) d1[j] = imgq[CAPW / 8 + j];
        for (int j = tid; j < CAPW / 8; j += 512) d2[j] = imgq[2 * (CAPW / 8) + j];
    }
}

// -------- mega: 64-node windows (4 blk/CU, grid 1564), pair stream + MFMA --------
// noff/ngrp are per-node absolute offsets, so mega's window size is independent
// of pack's. Wave wv streams 8 nodes; MFMA splits cols across wave pairs.
__global__ __launch_bounds__(512) void k_mega(
        const int* __restrict__ noff, const unsigned char* __restrict__ ngrp,
        const unsigned short* __restrict__ rec2s,
        const unsigned short* __restrict__ rec2x,
        const unsigned short* __restrict__ rec2f,
        const float2* __restrict__ sx,
        const float* __restrict__ W1_rel, const float* __restrict__ W1_root,
        const float* __restrict__ b1,
        const float* __restrict__ W2_rel, const float* __restrict__ b2,
        const float* __restrict__ W2_root,
        const float* __restrict__ W3_rel, const float* __restrict__ W3_root,
        const float* __restrict__ b3,
        float* __restrict__ p, float* __restrict__ out) {
    __shared__ _Float16 aggh[WNP * AP];       // 9216 B
    __shared__ _Float16 Bt[HID * BPITCH];     // 17408 B
    __shared__ float2 sxl[WNP];               // 512 B
    __shared__ float partP[2][WNP];           // 512 B
    __shared__ float partR[2][WNP];           // 512 B -> ~28.2 KB, 4 blk/CU
    const int tid = threadIdx.x;
    const int f = tid & 63;
    const int wv = tid >> 6;                  // 0..7
    const int gi0 = blockIdx.x * WNP;

    for (int j = tid; j < WNP * AP / 2; j += 512) ((int*)aggh)[j] = 0;
    for (int idx = tid; idx < HID * HID; idx += 512) {
        int k = idx >> 6, n = idx & 63;
        Bt[n * BPITCH + k]       = (_Float16)W2_rel[idx];
        Bt[n * BPITCH + HID + k] = (_Float16)W2_root[idx];
    }
    if (tid < WNP) {
        int gi = gi0 + tid;
        sxl[tid] = (gi < NN) ? sx[gi] : make_float2(0.f, 0.f);
    }
    const float w1rf = W1_rel[f], w1tf = W1_root[f], b1ff = b1[f];
    const float b3v = b3[0];
    __syncthreads();

    {
        const int first = gi0 + wv * 8;
        int soff = __builtin_amdgcn_readfirstlane(noff[first]);
        const int2 gv = *(const int2*)(ngrp + first);
        unsigned ua = __builtin_amdgcn_readfirstlane((unsigned)gv.x);
        unsigned ub = __builtin_amdgcn_readfirstlane((unsigned)gv.y);
        unsigned long long clo = (unsigned long long)ua | ((unsigned long long)ub << 32);
        #define BSUM(u) (((u) & 255u) + (((u) >> 8) & 255u) + (((u) >> 16) & 255u) + ((u) >> 24))
        const int tg = (int)(BSUM(ua) + BSUM(ub));
        #undef BSUM

        const h2v w1r2 = {(_Float16)w1rf, (_Float16)w1rf};
        const h2v w1t2 = {(_Float16)w1tf, (_Float16)w1tf};
        const h2v b1f2 = {(_Float16)b1ff, (_Float16)b1ff};
        const h2v one2 = {(_Float16)1.f, (_Float16)1.f};
        const h2v zero2 = {(_Float16)0.f, (_Float16)0.f};

        float a0 = 0.f, a1 = 0.f, a2 = 0.f, a3 = 0.f;
        int nrow = wv * 8;
        const int rowend = nrow + 8;
        int grem = (int)(clo & 255); clo >>= 8;
        while (grem == 0 && nrow + 1 < rowend) {
            ++nrow; grem = (int)(clo & 255); clo >>= 8;
        }

        // plane base pointers in int4 units (8 slots = 16 B per plane per group)
        const int4* ps = (const int4*)rec2s + (soff >> 3);
        const int4* px = (const int4*)rec2x + (soff >> 3);
        const int4* pf = (const int4*)rec2f + (soff >> 3);

        int4 S0, X0, F0, S1, X1, F1, S2, X2, F2, S3, X3, F3;
        if (tg >= 1) { S0 = ps[0]; X0 = px[0]; F0 = pf[0]; }
        if (tg >= 2) { S1 = ps[1]; X1 = px[1]; F1 = pf[1]; }
        if (tg >= 3) { S2 = ps[2]; X2 = px[2]; F2 = pf[2]; }

#define PP(SS, XX, FF, AA) {                                 \
        h2v z_ = ash2((unsigned)(FF)) * b1f2;                \
        z_ = ash2((unsigned)(XX)) * w1t2 + z_;               \
        z_ = ash2((unsigned)(SS)) * w1r2 + z_;               \
        z_ = __builtin_elementwise_max(z_, zero2);           \
        AA = __builtin_amdgcn_fdot2(z_, one2, AA, false); }

#define GRP(S, X, F)                                         \
        PP(S.x, X.x, F.x, a0) PP(S.y, X.y, F.y, a1)          \
        PP(S.z, X.z, F.z, a2) PP(S.w, X.w, F.w, a3)

#define BNDRY() {                                                        \
        if (--grem == 0) {                                               \
            aggh[nrow * AP + f] = (_Float16)((a0 + a1) + (a2 + a3));     \
            a0 = a1 = a2 = a3 = 0.f;                                     \
            ++nrow; grem = (int)(clo & 255); clo >>= 8;                  \
            while (grem == 0 && nrow + 1 < rowend) {                     \
                ++nrow; grem = (int)(clo & 255); clo >>= 8;              \
            }                                                            \
        } }

        int t = 0;
        // steady state: 4 groups in flight (overrun reads land in plane slack)
        while (t + 4 <= tg) {
            S3 = ps[t + 3]; X3 = px[t + 3]; F3 = pf[t + 3];
            GRP(S0, X0, F0) BNDRY(); ++t;
            S0 = ps[t + 3]; X0 = px[t + 3]; F0 = pf[t + 3];
            GRP(S1, X1, F1) BNDRY(); ++t;
            S1 = ps[t + 3]; X1 = px[t + 3]; F1 = pf[t + 3];
            GRP(S2, X2, F2) BNDRY(); ++t;
            S2 = ps[t + 3]; X2 = px[t + 3]; F2 = pf[t + 3];
            GRP(S3, X3, F3) BNDRY(); ++t;
        }
        if (t < tg) {
            GRP(S0, X0, F0) BNDRY(); ++t;
            if (t < tg) {
                GRP(S1, X1, F1) BNDRY(); ++t;
                if (t < tg) {
                    GRP(S2, X2, F2) BNDRY(); ++t;
                }
            }
        }
#undef PP
#undef GRP
#undef BNDRY
    }
    __syncthreads();

    // MFMA: wave wv -> rows (wv&3)*16..+15, cols (wv>>2)*32..+31 (2 col-tiles)
    const int m16 = tid & 15;
    const int quad = (tid & 63) >> 4;
    const int rw = wv & 3;                    // row block
    const int cw = wv >> 2;                   // column half
    f32x4 acc[2];
    acc[0] = (f32x4){0.f, 0.f, 0.f, 0.f};
    acc[1] = (f32x4){0.f, 0.f, 0.f, 0.f};

    const float2 sm = sxl[rw * 16 + m16];

    #pragma unroll
    for (int kt = 0; kt < 4; ++kt) {
        const int kk = kt * 32;
        half8 af;
        if (kt < 2) {
            af = *(const half8*)&aggh[(rw * 16 + m16) * AP + kk + quad * 8];
        } else {
            const int fk0 = (kt - 2) * 32 + quad * 8;
            #pragma unroll
            for (int j = 0; j < 8; ++j) {
                const float wr = W1_rel[fk0 + j], wt = W1_root[fk0 + j], bb = b1[fk0 + j];
                af[j] = (_Float16)fmaxf(0.f, fmaf(sm.x, wr, fmaf(sm.y, wt, bb)));
            }
        }
        #pragma unroll
        for (int c = 0; c < 2; ++c) {
            const int ct = cw * 2 + c;
            const half8 bfrag = *(const half8*)&Bt[(ct * 16 + m16) * BPITCH + kk + quad * 8];
            acc[c] = __builtin_amdgcn_mfma_f32_16x16x32_f16(af, bfrag, acc[c], 0, 0, 0);
        }
    }

    float b2c[2], w3rc[2], w3tc[2];
    #pragma unroll
    for (int c = 0; c < 2; ++c) {
        const int col = (cw * 2 + c) * 16 + m16;
        b2c[c] = b2[col]; w3rc[c] = W3_rel[col]; w3tc[c] = W3_root[col];
    }
    float pv[4] = {0.f, 0.f, 0.f, 0.f}, rv[4] = {0.f, 0.f, 0.f, 0.f};
    #pragma unroll
    for (int c = 0; c < 2; ++c) {
        #pragma unroll
        for (int reg = 0; reg < 4; ++reg) {
            const float h2_ = fmaxf(0.f, acc[c][reg] + b2c[c]);
            pv[reg] = fmaf(h2_, w3rc[c], pv[reg]);
            rv[reg] = fmaf(h2_, w3tc[c], rv[reg]);
        }
    }
    #pragma unroll
    for (int reg = 0; reg < 4; ++reg) {
        #pragma unroll
        for (int msk = 1; msk < 16; msk <<= 1) {
            pv[reg] += __shfl_xor(pv[reg], msk, 64);
            rv[reg] += __shfl_xor(rv[reg], msk, 64);
        }
    }
    if (m16 == 0) {
        #pragma unroll
        for (int reg = 0; reg < 4; ++reg) {
            const int row = rw * 16 + quad * 4 + reg;
            partP[cw][row] = pv[reg];
            partR[cw][row] = rv[reg];
        }
    }
    __syncthreads();
    if (tid < WNP) {
        const int gi = gi0 + tid;
        if (gi < NN) {
            p[gi]   = partP[0][tid] + partP[1][tid];
            out[gi] = partR[0][tid] + partR[1][tid] + b3v;
        }
    }
}

// -------- split out: 4 blocks/bucket; out += seg_sum(w * p[src]) via atomics ----
__global__ __launch_bounds__(512) void k_out(const int* __restrict__ gcur,
                                             const int* __restrict__ rec_a,
                                             const unsigned short* __restrict__ rec_w,
                                             const float* __restrict__ pp,
                                             float* __restrict__ out) {
    __shared__ float loc[NPB];
    if (threadIdx.x < NPB) loc[threadIdx.x] = 0.f;
    __syncthreads();
    const int wid = blockIdx.x;
    const int b = wid >> 2, j = wid & 3;
    const int beg = b * CAP, cnt = gcur[b] - beg;
    const int qtr = (cnt + 3) >> 2;
    const int s0 = beg + min(cnt, j * qtr);
    const int s1e = beg + min(cnt, (j + 1) * qtr);
    for (int t = s0 + threadIdx.x; t < s1e; t += 512) {
        const int a = rec_a[t];
        const float w = h2f(rec_w[t]);
        atomicAdd(&loc[a >> 17], w * pp[a & SRCM]);
    }
    __syncthreads();
    const int i = b * NPB + threadIdx.x;
    if (threadIdx.x < NPB && i < NN) {
        float v = loc[threadIdx.x];
        if (v != 0.f) atomicAdd(&out[i], v);
    }
}

extern "C" void kernel_launch(void* const* d_in, const int* in_sizes, int n_in,
                              void* d_out, int out_size, void* d_ws, size_t ws_size,
                              hipStream_t stream) {
    const float* x       = (const float*)d_in[0];
    const int*   ei      = (const int*)  d_in[1];
    const float* ew      = (const float*)d_in[2];
    const float* W1_rel  = (const float*)d_in[3];
    const float* b1      = (const float*)d_in[4];
    const float* W1_root = (const float*)d_in[5];
    const float* W2_rel  = (const float*)d_in[6];
    const float* b2      = (const float*)d_in[7];
    const float* W2_root = (const float*)d_in[8];
    const float* W3_rel  = (const float*)d_in[9];
    const float* b3      = (const float*)d_in[10];
    const float* W3_root = (const float*)d_in[11];

    const int* src = ei;
    const int* dst = ei + NE;

    // workspace layout (~48 MB of the ~268 MB workspace)
    const size_t REC_SLOTS = (size_t)NB * CAP;            // 3.60M slots
    const size_t PLANE     = (size_t)NMW * CAPW;          // 4.00M u16 slots / plane
    int*            rec_a = (int*)d_ws;                   // 14.4 MB
    unsigned short* rec_w = (unsigned short*)(rec_a + REC_SLOTS); // 7.2 MB
    float2*         sx    = (float2*)(rec_w + REC_SLOTS); // 800 KB
    float*          p     = (float*)(sx + NN);            // 400 KB
    int*            noff  = (int*)(p + NN);               // NNP*4
    unsigned char*  ngrp  = (unsigned char*)(noff + NNP); // NNP
    int*            gcur  = (int*)(ngrp + NNP);           // NB*4
    char*           tail  = (char*)(gcur + NB);
    size_t          off   = ((size_t)(tail - (char*)d_ws) + 15) & ~(size_t)15;
    unsigned short* rec2s = (unsigned short*)((char*)d_ws + off);   // 8.0 MB
    unsigned short* rec2x = rec2s + PLANE;                          // 8.0 MB
    unsigned short* rec2f = rec2x + PLANE;                          // 8.0 MB

    k_init<<<(NN + 511) / 512, 512, 0, stream>>>(x, sx, gcur);
    k_scatter<<<NCH, 512, 0, stream>>>(src, dst, ew, gcur, rec_a, rec_w);
    k_s1<<<4 * NB, 512, 0, stream>>>(gcur, rec_a, rec_w, x, (float*)sx);
    k_pack<<<NMW, 512, 0, stream>>>(gcur, rec_a, rec_w, sx,
                                    rec2s, rec2x, rec2f, noff, ngrp);
    k_mega<<<NW2, 512, 0, stream>>>(noff, ngrp, rec2s, rec2x, rec2f, sx,
                                    W1_rel, W1_root, b1,
                                    W2_rel, b2, W2_root,
                                    W3_rel, W3_root, b3, p, (float*)d_out);
    k_out<<<4 * NB, 512, 0, stream>>>(gcur, rec_a, rec_w, p, (float*)d_out);
}

// Round 12
// 231.687 us; speedup vs baseline: 6.5503x; 1.0121x over previous
//
#include <hip/hip_runtime.h>

#define NN 100000
#define NE 3200000
#define HID 64
#define NPB 256                         // nodes per bucket (dl = dst & 255)
#define NB  ((NN + NPB - 1) / NPB)      // 391 buckets
#define NNP (NB * NPB)                  // 100096 padded node slots
#define CAP 9216                        // bucket capacity: mean 8192, +11 sigma
#define MNP 128                         // nodes per pack window
#define NMW (2 * NB)                    // 782 pack windows
#define WNP 64                          // nodes per mega window (R11: occupancy)
#define NW2 (NNP / WNP)                 // 1564 mega windows
#define CAPW 5120                       // padded slots per pack window
#define CHUNK 4096                      // edges per scatter workgroup (R5-proven)
#define NCH ((NE + CHUNK - 1) / CHUNK)  // 782 chunks
#define AP 72                           // f16 agg row pitch in halfs (144 B)
#define BPITCH 136                      // f16 Bt row pitch in halfs (272 B)
#define SRCM 0x1FFFF                    // src mask (17 bits; NN < 2^17)

typedef _Float16 half8 __attribute__((ext_vector_type(8)));
typedef _Float16 h2v   __attribute__((ext_vector_type(2)));
typedef float f32x4 __attribute__((ext_vector_type(4)));

__device__ __forceinline__ unsigned short f2hb(float v) {
    _Float16 h = (_Float16)v;
    unsigned short s;
    __builtin_memcpy(&s, &h, 2);
    return s;
}
__device__ __forceinline__ float h2f(unsigned int u) {
    unsigned short s = (unsigned short)u;
    _Float16 h;
    __builtin_memcpy(&h, &s, 2);
    return (float)h;
}
__device__ __forceinline__ h2v ash2(unsigned int u) {
    h2v r;
    __builtin_memcpy(&r, &u, 4);
    return r;
}

// -------- init: sx = (0, x); zero deg; bucket cursors --------
__global__ __launch_bounds__(512) void k_init(const float* __restrict__ x,
                                              float2* __restrict__ sx,
                                              int* __restrict__ deg,
                                              int* __restrict__ gcur) {
    const int i = blockIdx.x * 512 + threadIdx.x;
    if (i < NN) sx[i] = make_float2(0.f, x[i]);
    if (i < NNP) deg[i] = 0;
    if (blockIdx.x == 0 && threadIdx.x < NB) gcur[threadIdx.x] = threadIdx.x * CAP;
}

// -------- scatter: in-LDS counting sort -> bucket-grouped SoA emission ----
__global__ __launch_bounds__(512) void k_scatter(const int* __restrict__ src,
                                                 const int* __restrict__ dst,
                                                 const float* __restrict__ ew,
                                                 int* __restrict__ gcur,
                                                 int* __restrict__ rec_a,
                                                 unsigned short* __restrict__ rec_w) {
    __shared__ int la[CHUNK];                 // 16 KB
    __shared__ unsigned short lw[CHUNK];      // 8 KB
    __shared__ unsigned short lb[CHUNK];      // 8 KB  (bucket id per record)
    __shared__ unsigned short sidx[CHUNK];    // 8 KB  (sorted-order -> record idx)
    __shared__ int cnt[NB];                   // counts, then cursor (=excl)
    __shared__ int bme[NB];                   // base - excl
    __shared__ int wt8[8];                    // wave scan partials
    const int tid = threadIdx.x;
    const int lane = tid & 63, wvx = tid >> 6;   // 8 waves
    for (int j = tid; j < NB; j += 512) cnt[j] = 0;
    __syncthreads();
    const long long b0 = (long long)blockIdx.x * CHUNK;
    const int valid = (int)min((long long)CHUNK, (long long)NE - b0);
    #pragma unroll
    for (int k = 0; k < CHUNK / 512; ++k) {
        int idx = k * 512 + tid;
        if (idx < valid) {
            long long e = b0 + idx;
            int d = dst[e];
            int b = d >> 8;
            la[idx] = src[e] | ((d & 255) << 17);
            lw[idx] = f2hb(ew[e]);
            lb[idx] = (unsigned short)b;
            atomicAdd(&cnt[b], 1);
        }
    }
    __syncthreads();
    // exclusive scan over NB=391 slots: one value per thread, 8-wave shfl scan
    const int v = (tid < NB) ? cnt[tid] : 0;
    int incl = v;
    #pragma unroll
    for (int off = 1; off < 64; off <<= 1) {
        int t0 = __shfl_up(incl, off, 64);
        if (lane >= off) incl += t0;
    }
    if (lane == 63) wt8[wvx] = incl;
    __syncthreads();
    int offs = 0;
    #pragma unroll
    for (int j = 0; j < 8; ++j)
        if (j < wvx) offs += wt8[j];
    const int excl = offs + incl - v;
    if (tid < NB) {
        int bb = v ? atomicAdd(&gcur[tid], v) : 0;
        bme[tid] = bb - excl;
        cnt[tid] = excl;                      // cursor
    }
    __syncthreads();
    // placement: sorted position per record
    #pragma unroll
    for (int k = 0; k < CHUNK / 512; ++k) {
        int idx = k * 512 + tid;
        if (idx < valid) {
            int sp = atomicAdd(&cnt[lb[idx]], 1);
            sidx[sp] = (unsigned short)idx;
        }
    }
    __syncthreads();
    // emission in bucket order: consecutive lanes -> consecutive addresses per run
    #pragma unroll
    for (int k = 0; k < CHUNK / 512; ++k) {
        int sp = k * 512 + tid;
        if (sp < valid) {
            int idx = sidx[sp];
            int b = lb[idx];
            int go = bme[b] + sp;
            rec_a[go] = la[idx];
            rec_w[go] = lw[idx];
        }
    }
}

// -------- split s1: 4 blocks/bucket; also accumulates per-node degree ----
__global__ __launch_bounds__(512) void k_s1(const int* __restrict__ gcur,
                                            const int* __restrict__ rec_a,
                                            const unsigned short* __restrict__ rec_w,
                                            const float* __restrict__ x,
                                            float* __restrict__ sxf,
                                            int* __restrict__ deg) {
    __shared__ float loc[NPB];
    __shared__ int ideg[NPB];
    if (threadIdx.x < NPB) { loc[threadIdx.x] = 0.f; ideg[threadIdx.x] = 0; }
    __syncthreads();
    const int wid = blockIdx.x;
    const int b = wid >> 2, j = wid & 3;
    const int beg = b * CAP, cnt = gcur[b] - beg;
    const int qtr = (cnt + 3) >> 2;
    const int s0 = beg + min(cnt, j * qtr);
    const int s1e = beg + min(cnt, (j + 1) * qtr);
    for (int t = s0 + threadIdx.x; t < s1e; t += 512) {
        const int a = rec_a[t];
        const float w = h2f(rec_w[t]);
        const int dl = a >> 17;
        atomicAdd(&loc[dl], w * x[a & SRCM]);
        atomicAdd(&ideg[dl], 1);
    }
    __syncthreads();
    const int i = b * NPB + threadIdx.x;
    if (threadIdx.x < NPB) {
        float v = loc[threadIdx.x];
        if (v != 0.f && i < NN) atomicAdd(&sxf[2 * i], v);
        int dv = ideg[threadIdx.x];
        if (dv) atomicAdd(&deg[i], dv);       // i < NNP always
    }
}

// -------- pack: deg-driven scan (no hist pass) + LDS image + coalesced dump ----
__global__ __launch_bounds__(512) void k_pack(const int* __restrict__ gcur,
                                              const int* __restrict__ deg,
                                              const int* __restrict__ rec_a,
                                              const unsigned short* __restrict__ rec_w,
                                              const float2* __restrict__ sx,
                                              unsigned short* __restrict__ rec2s,
                                              unsigned short* __restrict__ rec2x,
                                              unsigned short* __restrict__ rec2f,
                                              int* __restrict__ noff,
                                              unsigned char* __restrict__ ngrp) {
    __shared__ int4 imgq[3 * CAPW / 8];       // 30720 B (3 planes x CAPW u16)
    __shared__ int exclp[128];
    __shared__ int cur[128];
    __shared__ int wt2[2];
    unsigned short* img = (unsigned short*)imgq;
    unsigned short* ws_img = img;
    unsigned short* wx_img = img + CAPW;
    unsigned short* wf_img = img + 2 * CAPW;
    const int tid = threadIdx.x;
    const int lane = tid & 63, wv = tid >> 6;
    const int wid = blockIdx.x;
    const int b = wid >> 1, h = wid & 1;
    for (int j = tid; j < 3 * CAPW / 8; j += 512) imgq[j] = (int4){0, 0, 0, 0};
    __syncthreads();
    const int beg = b * CAP;
    const int cnt = gcur[b] - beg;
    // padded exclusive scan over 128 bins from precomputed deg (s1-supplied)
    int pc = 0, incl = 0;
    if (tid < 128) { pc = (deg[wid * MNP + tid] + 7) & ~7; incl = pc; }
    #pragma unroll
    for (int off = 1; off < 64; off <<= 1) {
        int tt = __shfl_up(incl, off, 64);
        if (lane >= off) incl += tt;
    }
    if (tid < 128 && lane == 63) wt2[wv] = incl;
    __syncthreads();
    if (tid < 128) {
        int e0 = ((tid >= 64) ? wt2[0] : 0) + incl - pc;
        exclp[tid] = e0;
        cur[tid] = e0;
        const int node = wid * MNP + tid;
        noff[node] = wid * CAPW + e0;         // absolute slot offset (mult of 8)
        ngrp[node] = (unsigned char)(pc >> 3);
    }
    __syncthreads();
    // single pass: stream rec SoA (4 records/iter), gather sx, scatter into LDS
#define PREC(AA, WW) {                                                  \
        const int dl_ = (AA) >> 17;                                     \
        if ((dl_ >> 7) == h) {                                          \
            const float w_ = h2f(WW);                                   \
            const float2 v_ = sx[(AA) & SRCM];                          \
            int gs_ = atomicAdd(&cur[dl_ & 127], 1);                    \
            ws_img[gs_] = f2hb(w_ * v_.x);                              \
            wx_img[gs_] = f2hb(w_ * v_.y);                              \
            wf_img[gs_] = (unsigned short)(WW);                         \
        } }
    {
        const int4* a4 = (const int4*)(rec_a + beg);
        const ushort4* w4 = (const ushort4*)(rec_w + beg);
        const int n4 = cnt >> 2;
        for (int t = tid; t < n4; t += 512) {
            int4 qa = a4[t];
            ushort4 qw = w4[t];
            PREC(qa.x, qw.x)
            PREC(qa.y, qw.y)
            PREC(qa.z, qw.z)
            PREC(qa.w, qw.w)
        }
        for (int t = (n4 << 2) + tid; t < cnt; t += 512) {
            PREC(rec_a[beg + t], rec_w[beg + t])
        }
    }
#undef PREC
    __syncthreads();
    // coalesced dump: 3 x 10240 B per window
    {
        const size_t pb = (size_t)wid * (CAPW / 8);   // int4 index into plane
        int4* d0 = (int4*)rec2s + pb;
        int4* d1 = (int4*)rec2x + pb;
        int4* d2 = (int4*)rec2f + pb;
        for (int j = tid; j < CAPW / 8; j += 512) d0[j] = imgq[j];
        for (int j = tid; j < CAPW / 8; j += 512) d1[j] = imgq[CAPW / 8 + j];
        for (int j = tid; j < CAPW / 8; j += 512) d2[j] = imgq[2 * (CAPW / 8) + j];
    }
}

// -------- mega: 64-node windows (4 blk/CU, grid 1564), pair stream + MFMA --------
__global__ __launch_bounds__(512) void k_mega(
        const int* __restrict__ noff, const unsigned char* __restrict__ ngrp,
        const unsigned short* __restrict__ rec2s,
        const unsigned short* __restrict__ rec2x,
        const unsigned short* __restrict__ rec2f,
        const float2* __restrict__ sx,
        const float* __restrict__ W1_rel, const float* __restrict__ W1_root,
        const float* __restrict__ b1,
        const float* __restrict__ W2_rel, const float* __restrict__ b2,
        const float* __restrict__ W2_root,
        const float* __restrict__ W3_rel, const float* __restrict__ W3_root,
        const float* __restrict__ b3,
        float* __restrict__ p, float* __restrict__ out) {
    __shared__ _Float16 aggh[WNP * AP];       // 9216 B
    __shared__ _Float16 Bt[HID * BPITCH];     // 17408 B
    __shared__ float2 sxl[WNP];               // 512 B
    __shared__ float partP[2][WNP];           // 512 B
    __shared__ float partR[2][WNP];           // 512 B -> ~28.2 KB, 4 blk/CU
    const int tid = threadIdx.x;
    const int f = tid & 63;
    const int wv = tid >> 6;                  // 0..7
    const int gi0 = blockIdx.x * WNP;

    for (int j = tid; j < WNP * AP / 2; j += 512) ((int*)aggh)[j] = 0;
    for (int idx = tid; idx < HID * HID; idx += 512) {
        int k = idx >> 6, n = idx & 63;
        Bt[n * BPITCH + k]       = (_Float16)W2_rel[idx];
        Bt[n * BPITCH + HID + k] = (_Float16)W2_root[idx];
    }
    if (tid < WNP) {
        int gi = gi0 + tid;
        sxl[tid] = (gi < NN) ? sx[gi] : make_float2(0.f, 0.f);
    }
    const float w1rf = W1_rel[f], w1tf = W1_root[f], b1ff = b1[f];
    const float b3v = b3[0];
    __syncthreads();

    {
        const int first = gi0 + wv * 8;
        int soff = __builtin_amdgcn_readfirstlane(noff[first]);
        const int2 gv = *(const int2*)(ngrp + first);
        unsigned ua = __builtin_amdgcn_readfirstlane((unsigned)gv.x);
        unsigned ub = __builtin_amdgcn_readfirstlane((unsigned)gv.y);
        unsigned long long clo = (unsigned long long)ua | ((unsigned long long)ub << 32);
        #define BSUM(u) (((u) & 255u) + (((u) >> 8) & 255u) + (((u) >> 16) & 255u) + ((u) >> 24))
        const int tg = (int)(BSUM(ua) + BSUM(ub));
        #undef BSUM

        const h2v w1r2 = {(_Float16)w1rf, (_Float16)w1rf};
        const h2v w1t2 = {(_Float16)w1tf, (_Float16)w1tf};
        const h2v b1f2 = {(_Float16)b1ff, (_Float16)b1ff};
        const h2v one2 = {(_Float16)1.f, (_Float16)1.f};
        const h2v zero2 = {(_Float16)0.f, (_Float16)0.f};

        float a0 = 0.f, a1 = 0.f, a2 = 0.f, a3 = 0.f;
        int nrow = wv * 8;
        const int rowend = nrow + 8;
        int grem = (int)(clo & 255); clo >>= 8;
        while (grem == 0 && nrow + 1 < rowend) {
            ++nrow; grem = (int)(clo & 255); clo >>= 8;
        }

        // plane base pointers in int4 units (8 slots = 16 B per plane per group)
        const int4* ps = (const int4*)rec2s + (soff >> 3);
        const int4* px = (const int4*)rec2x + (soff >> 3);
        const int4* pf = (const int4*)rec2f + (soff >> 3);

        int4 S0, X0, F0, S1, X1, F1, S2, X2, F2, S3, X3, F3;
        if (tg >= 1) { S0 = ps[0]; X0 = px[0]; F0 = pf[0]; }
        if (tg >= 2) { S1 = ps[1]; X1 = px[1]; F1 = pf[1]; }
        if (tg >= 3) { S2 = ps[2]; X2 = px[2]; F2 = pf[2]; }

#define PP(SS, XX, FF, AA) {                                 \
        h2v z_ = ash2((unsigned)(FF)) * b1f2;                \
        z_ = ash2((unsigned)(XX)) * w1t2 + z_;               \
        z_ = ash2((unsigned)(SS)) * w1r2 + z_;               \
        z_ = __builtin_elementwise_max(z_, zero2);           \
        AA = __builtin_amdgcn_fdot2(z_, one2, AA, false); }

#define GRP(S, X, F)                                         \
        PP(S.x, X.x, F.x, a0) PP(S.y, X.y, F.y, a1)          \
        PP(S.z, X.z, F.z, a2) PP(S.w, X.w, F.w, a3)

#define BNDRY() {                                                        \
        if (--grem == 0) {                                               \
            aggh[nrow * AP + f] = (_Float16)((a0 + a1) + (a2 + a3));     \
            a0 = a1 = a2 = a3 = 0.f;                                     \
            ++nrow; grem = (int)(clo & 255); clo >>= 8;                  \
            while (grem == 0 && nrow + 1 < rowend) {                     \
                ++nrow; grem = (int)(clo & 255); clo >>= 8;              \
            }                                                            \
        } }

        int t = 0;
        // steady state: 4 groups in flight (overrun reads land in plane slack)
        while (t + 4 <= tg) {
            S3 = ps[t + 3]; X3 = px[t + 3]; F3 = pf[t + 3];
            GRP(S0, X0, F0) BNDRY(); ++t;
            S0 = ps[t + 3]; X0 = px[t + 3]; F0 = pf[t + 3];
            GRP(S1, X1, F1) BNDRY(); ++t;
            S1 = ps[t + 3]; X1 = px[t + 3]; F1 = pf[t + 3];
            GRP(S2, X2, F2) BNDRY(); ++t;
            S2 = ps[t + 3]; X2 = px[t + 3]; F2 = pf[t + 3];
            GRP(S3, X3, F3) BNDRY(); ++t;
        }
        if (t < tg) {
            GRP(S0, X0, F0) BNDRY(); ++t;
            if (t < tg) {
                GRP(S1, X1, F1) BNDRY(); ++t;
                if (t < tg) {
                    GRP(S2, X2, F2) BNDRY(); ++t;
                }
            }
        }
#undef PP
#undef GRP
#undef BNDRY
    }
    __syncthreads();

    // MFMA: wave wv -> rows (wv&3)*16..+15, cols (wv>>2)*32..+31 (2 col-tiles)
    const int m16 = tid & 15;
    const int quad = (tid & 63) >> 4;
    const int rw = wv & 3;                    // row block
    const int cw = wv >> 2;                   // column half
    f32x4 acc[2];
    acc[0] = (f32x4){0.f, 0.f, 0.f, 0.f};
    acc[1] = (f32x4){0.f, 0.f, 0.f, 0.f};

    const float2 sm = sxl[rw * 16 + m16];

    #pragma unroll
    for (int kt = 0; kt < 4; ++kt) {
        const int kk = kt * 32;
        half8 af;
        if (kt < 2) {
            af = *(const half8*)&aggh[(rw * 16 + m16) * AP + kk + quad * 8];
        } else {
            const int fk0 = (kt - 2) * 32 + quad * 8;
            #pragma unroll
            for (int j = 0; j < 8; ++j) {
                const float wr = W1_rel[fk0 + j], wt = W1_root[fk0 + j], bb = b1[fk0 + j];
                af[j] = (_Float16)fmaxf(0.f, fmaf(sm.x, wr, fmaf(sm.y, wt, bb)));
            }
        }
        #pragma unroll
        for (int c = 0; c < 2; ++c) {
            const int ct = cw * 2 + c;
            const half8 bfrag = *(const half8*)&Bt[(ct * 16 + m16) * BPITCH + kk + quad * 8];
            acc[c] = __builtin_amdgcn_mfma_f32_16x16x32_f16(af, bfrag, acc[c], 0, 0, 0);
        }
    }

    float b2c[2], w3rc[2], w3tc[2];
    #pragma unroll
    for (int c = 0; c < 2; ++c) {
        const int col = (cw * 2 + c) * 16 + m16;
        b2c[c] = b2[col]; w3rc[c] = W3_rel[col]; w3tc[c] = W3_root[col];
    }
    float pv[4] = {0.f, 0.f, 0.f, 0.f}, rv[4] = {0.f, 0.f, 0.f, 0.f};
    #pragma unroll
    for (int c = 0; c < 2; ++c) {
        #pragma unroll
        for (int reg = 0; reg < 4; ++reg) {
            const float h2_ = fmaxf(0.f, acc[c][reg] + b2c[c]);
            pv[reg] = fmaf(h2_, w3rc[c], pv[reg]);
            rv[reg] = fmaf(h2_, w3tc[c], rv[reg]);
        }
    }
    #pragma unroll
    for (int reg = 0; reg < 4; ++reg) {
        #pragma unroll
        for (int msk = 1; msk < 16; msk <<= 1) {
            pv[reg] += __shfl_xor(pv[reg], msk, 64);
            rv[reg] += __shfl_xor(rv[reg], msk, 64);
        }
    }
    if (m16 == 0) {
        #pragma unroll
        for (int reg = 0; reg < 4; ++reg) {
            const int row = rw * 16 + quad * 4 + reg;
            partP[cw][row] = pv[reg];
            partR[cw][row] = rv[reg];
        }
    }
    __syncthreads();
    if (tid < WNP) {
        const int gi = gi0 + tid;
        if (gi < NN) {
            p[gi]   = partP[0][tid] + partP[1][tid];
            out[gi] = partR[0][tid] + partR[1][tid] + b3v;
        }
    }
}

// -------- split out: 4 blocks/bucket; out += seg_sum(w * p[src]) via atomics ----
__global__ __launch_bounds__(512) void k_out(const int* __restrict__ gcur,
                                             const int* __restrict__ rec_a,
                                             const unsigned short* __restrict__ rec_w,
                                             const float* __restrict__ pp,
                                             float* __restrict__ out) {
    __shared__ float loc[NPB];
    if (threadIdx.x < NPB) loc[threadIdx.x] = 0.f;
    __syncthreads();
    const int wid = blockIdx.x;
    const int b = wid >> 2, j = wid & 3;
    const int beg = b * CAP, cnt = gcur[b] - beg;
    const int qtr = (cnt + 3) >> 2;
    const int s0 = beg + min(cnt, j * qtr);
    const int s1e = beg + min(cnt, (j + 1) * qtr);
    for (int t = s0 + threadIdx.x; t < s1e; t += 512) {
        const int a = rec_a[t];
        const float w = h2f(rec_w[t]);
        atomicAdd(&loc[a >> 17], w * pp[a & SRCM]);
    }
    __syncthreads();
    const int i = b * NPB + threadIdx.x;
    if (threadIdx.x < NPB && i < NN) {
        float v = loc[threadIdx.x];
        if (v != 0.f) atomicAdd(&out[i], v);
    }
}

extern "C" void kernel_launch(void* const* d_in, const int* in_sizes, int n_in,
                              void* d_out, int out_size, void* d_ws, size_t ws_size,
                              hipStream_t stream) {
    const float* x       = (const float*)d_in[0];
    const int*   ei      = (const int*)  d_in[1];
    const float* ew      = (const float*)d_in[2];
    const float* W1_rel  = (const float*)d_in[3];
    const float* b1      = (const float*)d_in[4];
    const float* W1_root = (const float*)d_in[5];
    const float* W2_rel  = (const float*)d_in[6];
    const float* b2      = (const float*)d_in[7];
    const float* W2_root = (const float*)d_in[8];
    const float* W3_rel  = (const float*)d_in[9];
    const float* b3      = (const float*)d_in[10];
    const float* W3_root = (const float*)d_in[11];

    const int* src = ei;
    const int* dst = ei + NE;

    // workspace layout (~49 MB of the ~268 MB workspace)
    const size_t REC_SLOTS = (size_t)NB * CAP;            // 3.60M slots
    const size_t PLANE     = (size_t)NMW * CAPW;          // 4.00M u16 slots / plane
    int*            rec_a = (int*)d_ws;                   // 14.4 MB
    unsigned short* rec_w = (unsigned short*)(rec_a + REC_SLOTS); // 7.2 MB
    float2*         sx    = (float2*)(rec_w + REC_SLOTS); // 800 KB
    float*          p     = (float*)(sx + NN);            // 400 KB
    int*            noff  = (int*)(p + NN);               // NNP*4
    unsigned char*  ngrp  = (unsigned char*)(noff + NNP); // NNP
    int*            deg   = (int*)(ngrp + NNP);           // NNP*4
    int*            gcur  = deg + NNP;                    // NB*4
    char*           tail  = (char*)(gcur + NB);
    size_t          off   = ((size_t)(tail - (char*)d_ws) + 15) & ~(size_t)15;
    unsigned short* rec2s = (unsigned short*)((char*)d_ws + off);   // 8.0 MB
    unsigned short* rec2x = rec2s + PLANE;                          // 8.0 MB
    unsigned short* rec2f = rec2x + PLANE;                          // 8.0 MB

    k_init<<<(NNP + 511) / 512, 512, 0, stream>>>(x, sx, deg, gcur);
    k_scatter<<<NCH, 512, 0, stream>>>(src, dst, ew, gcur, rec_a, rec_w);
    k_s1<<<4 * NB, 512, 0, stream>>>(gcur, rec_a, rec_w, x, (float*)sx, deg);
    k_pack<<<NMW, 512, 0, stream>>>(gcur, deg, rec_a, rec_w, sx,
                                    rec2s, rec2x, rec2f, noff, ngrp);
    k_mega<<<NW2, 512, 0, stream>>>(noff, ngrp, rec2s, rec2x, rec2f, sx,
                                    W1_rel, W1_root, b1,
                                    W2_rel, b2, W2_root,
                                    W3_rel, W3_root, b3, p, (float*)d_out);
    k_out<<<4 * NB, 512, 0, stream>>>(gcur, rec_a, rec_w, p, (float*)d_out);
}